// Round 13
// baseline (289.574 us; speedup 1.0000x reference)
//
#include <hip/hip_runtime.h>
#include <hip/hip_fp16.h>
#include <math.h>

#define B_ 16
#define C_ 3
#define H_ 320
#define W_ 448
#define HW_ (H_*W_)
#define NITERS_ 5
#define LAMBDA_ 0.01f
#define HUBER_ 0.1f
#define EPS_ 1e-6f
#define INV_W1 (1.0f/(float)(W_-1))
#define INV_H1 (1.0f/(float)(H_-1))

#define BPB 112       // blocks per batch (1792 total) -- proven shape
#define CHUNK 1280    // pixels per block == 5*TPB; 112*1280 == H*W
#define TPB 256
#define PPT 5

// workspace layout
#define PARTIALS_OFF 2048
#define PLANE_OFF    262144
#define PLANE_U2     ((size_t)B_*HW_*3)            // uint2 elements (24B/px)
#define WS_NEED      (PLANE_OFF + PLANE_U2*8)

// fast reciprocal (v_rcp_f32, ~1e-7 rel err). Safe: GN iteration is a
// contraction -- per-iteration arithmetic noise doesn't move the converged
// pose (R12: fp16 planes gave absmax 0.0).
__device__ __forceinline__ float frcp(float x) { return __builtin_amdgcn_rcpf(x); }

// ---------------- SE(3) exp in double ----------------
__device__ __host__ inline void se3_exp_d(const double xi[6], double T[16]) {
    double vx = xi[0], vy = xi[1], vz = xi[2];
    double wx = xi[3], wy = xi[4], wz = xi[5];
    double th2  = wx*wx + wy*wy + wz*wz;
    double th2c = th2 > 1e-16 ? th2 : 1e-16;
    double th   = sqrt(th2c);
    bool   sm   = th2 < 1e-10;
    double A  = sm ? (1.0 - th2*(1.0/6.0))   : (sin(th)/th);
    double Bc = sm ? (0.5 - th2*(1.0/24.0))  : ((1.0 - cos(th))/th2c);
    double Cc = sm ? (1.0/6.0 - th2*(1.0/120.0)) : ((1.0 - A)/th2c);
    double K[9]  = {0.0,-wz,wy,  wz,0.0,-wx,  -wy,wx,0.0};
    double K2[9];
    #pragma unroll
    for (int i = 0; i < 3; ++i)
        #pragma unroll
        for (int j = 0; j < 3; ++j) {
            double s = 0.0;
            #pragma unroll
            for (int k = 0; k < 3; ++k) s += K[i*3+k]*K[k*3+j];
            K2[i*3+j] = s;
        }
    double R[9], V[9];
    #pragma unroll
    for (int i = 0; i < 9; ++i) {
        double I = (i == 0 || i == 4 || i == 8) ? 1.0 : 0.0;
        R[i] = I + A*K[i]  + Bc*K2[i];
        V[i] = I + Bc*K[i] + Cc*K2[i];
    }
    double tx = V[0]*vx + V[1]*vy + V[2]*vz;
    double ty = V[3]*vx + V[4]*vy + V[5]*vz;
    double tz = V[6]*vx + V[7]*vy + V[8]*vz;
    T[0]=R[0]; T[1]=R[1]; T[2] =R[2]; T[3] =tx;
    T[4]=R[3]; T[5]=R[4]; T[6] =R[5]; T[7] =ty;
    T[8]=R[6]; T[9]=R[7]; T[10]=R[8]; T[11]=tz;
    T[12]=0.0; T[13]=0.0; T[14]=0.0;  T[15]=1.0;
}

// ---------------- init: T = se3_exp(pose_twist) ----------------
__global__ void init_kernel(const float* __restrict__ pose,
                            float* __restrict__ Tcur, float* __restrict__ Tinit) {
    int b = threadIdx.x;
    if (b >= B_) return;
    double xi[6];
    #pragma unroll
    for (int k = 0; k < 6; ++k) xi[k] = (double)pose[b*6+k];
    double T[16];
    se3_exp_d(xi, T);
    #pragma unroll
    for (int k = 0; k < 16; ++k) {
        float f = (float)T[k];
        Tcur[b*16+k]  = f;
        Tinit[b*16+k] = f;
    }
}

// ---------------- precompute: fp16 12-ch plane {v,dx,dy} x {r,g,b,invD0} ----
#define PRE_BPB (HW_/TPB)   // 560
__device__ __forceinline__ unsigned pk16(float a, float b) {
    __half2 h = __floats2half2_rn(a, b);
    unsigned u; __builtin_memcpy(&u, &h, 4); return u;
}
__global__ __launch_bounds__(TPB)
void pack_kernel(const float* __restrict__ I0, const float* __restrict__ invD0,
                 uint2* __restrict__ P2)
{
    const int b   = blockIdx.x / PRE_BPB;
    const int rem = blockIdx.x % PRE_BPB;
    const int p   = rem*TPB + (int)threadIdx.x;
    const int y   = p / W_;
    const int x   = p - y*W_;
    const int xp  = (x < W_-1) ? 1 : 0;
    const int xm  = (x > 0) ? -1 : 0;
    const int yp  = (y < H_-1) ? W_ : 0;
    const int ym  = (y > 0) ? -W_ : 0;

    const float* s0 = I0    + (size_t)b*C_*HW_ + p;
    const float* sd = invD0 + (size_t)b*HW_   + p;

    const float v0 = s0[0], v1 = s0[HW_], v2 = s0[2*HW_], v3 = sd[0];
    const float dx0 = 0.5f*(s0[xp]       - s0[xm]);
    const float dx1 = 0.5f*(s0[HW_+xp]   - s0[HW_+xm]);
    const float dx2 = 0.5f*(s0[2*HW_+xp] - s0[2*HW_+xm]);
    const float dx3 = 0.5f*(sd[xp]       - sd[xm]);
    const float dy0 = 0.5f*(s0[yp]       - s0[ym]);
    const float dy1 = 0.5f*(s0[HW_+yp]   - s0[HW_+ym]);
    const float dy2 = 0.5f*(s0[2*HW_+yp] - s0[2*HW_+ym]);
    const float dy3 = 0.5f*(sd[yp]       - sd[ym]);

    const size_t o = ((size_t)b*HW_ + p)*3;
    P2[o+0] = make_uint2(pk16(v0,v1),  pk16(v2,v3));
    P2[o+1] = make_uint2(pk16(dx0,dx1),pk16(dx2,dx3));
    P2[o+2] = make_uint2(pk16(dy0,dy1),pk16(dy2,dy3));
}

__device__ __forceinline__ __half2 bc2(unsigned u) {
    __half2 h; __builtin_memcpy(&h, &u, 4); return h;
}
__device__ __forceinline__ float2 h2f(__half2 h) { return __half22float2(h); }

// ---------------- per-pixel GN accumulation (fp16 plane, packed blend) ----
// R12 structure + (a) all 9 IEEE divides -> v_rcp_f32 / constant-mul,
// (b) blend done in packed half2 FMA (24 v_pk_fma_f16 vs 48 cvt + 48 FMA).
// NO launch_bounds min-waves (R2/R3/R6 spill history).
__global__ __launch_bounds__(TPB)
void pixel_h16_kernel(const uint2* __restrict__ P2,
                      const float* __restrict__ I1, const float* __restrict__ invD1,
                      const float* __restrict__ intr,
                      const float* __restrict__ Tcur, const float* __restrict__ Tinit,
                      float* __restrict__ partials)
{
    // XCD-aware swizzle (bijective, 1792 % 8 == 0): contiguous chunks per XCD.
    const int nwg = B_*BPB;
    const int bid = blockIdx.x;
    const int swz = (bid & 7) * (nwg >> 3) + (bid >> 3);
    const int b   = swz / BPB;
    const int blk = swz % BPB;

    const float fx = intr[b*4+0], fy = intr[b*4+1];
    const float cx = intr[b*4+2], cy = intr[b*4+3];
    const float inv_fx = frcp(fx), inv_fy = frcp(fy);

    const float* Tc = Tcur  + b*16;
    const float* Ti = Tinit + b*16;
    const float Rc00=Tc[0], Rc01=Tc[1], Rc02=Tc[2],  tcx=Tc[3];
    const float Rc10=Tc[4], Rc11=Tc[5], Rc12=Tc[6],  tcy=Tc[7];
    const float Rc20=Tc[8], Rc21=Tc[9], Rc22=Tc[10], tcz=Tc[11];
    const float Ri00=Ti[0], Ri01=Ti[1], Ri02=Ti[2],  tix=Ti[3];
    const float Ri10=Ti[4], Ri11=Ti[5], Ri12=Ti[6],  tiy=Ti[7];
    const float Ri20=Ti[8], Ri21=Ti[9], Ri22=Ti[10], tiz=Ti[11];

    const uint2* Pb = P2 + (size_t)b*HW_*3;
    const float* P1 = I1    + (size_t)b*C_*HW_;
    const float* D1 = invD1 + (size_t)b*HW_;

    float acc[27];
    #pragma unroll
    for (int k = 0; k < 27; ++k) acc[k] = 0.0f;

    const int base = blk*CHUNK + (int)threadIdx.x;

    // d1 preload (protects each body's serial front head)
    float d1v[PPT];
    #pragma unroll
    for (int i = 0; i < PPT; ++i) d1v[i] = D1[base + i*TPB];

    auto body = [&](int i5) {
        const int p = base + i5*TPB;
        const int vcoord = p / W_;
        const int ucoord = p - vcoord*W_;

        // P1 loads issue first -- independent, overlap the gather wait
        const float p1a = P1[p];
        const float p1b = P1[HW_ + p];
        const float p1c = P1[2*HW_ + p];

        const float iD1 = d1v[i5];
        const float iD  = fmaxf(iD1, EPS_);
        const float z1  = frcp(iD);
        const float x1  = ((float)ucoord - cx)*inv_fx * z1;
        const float y1  = ((float)vcoord - cy)*inv_fy * z1;

        // current warp
        const float Xc0 = Rc00*x1 + Rc01*y1 + Rc02*z1 + tcx;
        const float Xc1 = Rc10*x1 + Rc11*y1 + Rc12*z1 + tcy;
        const float Xc2 = Rc20*x1 + Rc21*y1 + Rc22*z1 + tcz;
        const float z0s = (fabsf(Xc2) > EPS_) ? Xc2 : EPS_;
        const float izc = frcp(z0s);
        const float u0  = fx*Xc0*izc + cx;
        const float v0  = fy*Xc1*izc + cy;
        const bool valid = (Xc2 > EPS_) && (iD1 > EPS_);
        const bool inb   = (u0 > 0.0f) && (u0 < (float)(W_-1)) &&
                           (v0 > 0.0f) && (v0 < (float)(H_-1));
        const bool vm = valid && inb;

        // initial-T projection for Jacobian (fixed linearization point)
        const float Xi0 = Ri00*x1 + Ri01*y1 + Ri02*z1 + tix;
        const float Xi1 = Ri10*x1 + Ri11*y1 + Ri12*z1 + tiy;
        const float Xi2 = Ri20*x1 + Ri21*y1 + Ri22*z1 + tiz;
        const float zis = (fabsf(Xi2) > EPS_) ? Xi2 : EPS_;
        const float izi = frcp(zis);
        const float aJ = fx*izi;
        const float cJ = -fx*Xi0*izi*izi;
        const float bJ = fy*izi;
        const float dJ = -fy*Xi1*izi*izi;

        // normalized grid (clipped), back to pixel coords (const-mul division)
        const float gx = fminf(fmaxf((u0*INV_W1 - 0.5f)*2.0f, -2.0f), 2.0f);
        const float gy = fminf(fmaxf((v0*INV_H1 - 0.5f)*2.0f, -2.0f), 2.0f);
        const float ix = (gx + 1.0f)*0.5f*(float)(W_-1);
        const float iy = (gy + 1.0f)*0.5f*(float)(H_-1);
        const float x0f = floorf(ix), y0f = floorf(iy);
        const float wx1 = ix - x0f,  wy1 = iy - y0f;
        const float wx0 = 1.0f - wx1, wy0 = 1.0f - wy1;

        // per-tap masks (reference: tap inside [0,W-1]x[0,H-1])
        const bool bx0 = (x0f >= 0.0f)  && (x0f <= (float)(W_-1));
        const bool bx1 = (x0f >= -1.0f) && (x0f <= (float)(W_-2));
        const bool by0 = (y0f >= 0.0f)  && (y0f <= (float)(H_-1));
        const bool by1 = (y0f >= -1.0f) && (y0f <= (float)(H_-2));
        const float m00 = (bx0 && by0) ? wx0*wy0 : 0.0f;
        const float m10 = (bx1 && by0) ? wx1*wy0 : 0.0f;
        const float m01 = (bx0 && by1) ? wx0*wy1 : 0.0f;
        const float m11 = (bx1 && by1) ? wx1*wy1 : 0.0f;

        const int x0i = (int)x0f;
        const int y0i = (int)y0f;
        const int c0 = min(max(x0i,   0), W_-1);
        const int c1 = min(max(x0i+1, 0), W_-1);
        const int o0 = min(max(y0i,   0), H_-1) * W_;
        const int o1 = min(max(y0i+1, 0), H_-1) * W_;

        // single gather batch: 4 taps x (16B + 8B)
        const int q00 = (o0+c0)*3, q10 = (o0+c1)*3, q01 = (o1+c0)*3, q11 = (o1+c1)*3;
        uint4 A00, A10, A01, A11;       // v.rgbd + dx.rgbd
        uint2 C00, C10, C01, C11;       // dy.rgbd
        __builtin_memcpy(&A00, &Pb[q00], 16); C00 = Pb[q00+2];
        __builtin_memcpy(&A10, &Pb[q10], 16); C10 = Pb[q10+2];
        __builtin_memcpy(&A01, &Pb[q01], 16); C01 = Pb[q01+2];
        __builtin_memcpy(&A11, &Pb[q11], 16); C11 = Pb[q11+2];

        // packed half2 blend: 24 v_pk_fma_f16
        const __half2 mh00 = __float2half2_rn(m00);
        const __half2 mh10 = __float2half2_rn(m10);
        const __half2 mh01 = __float2half2_rn(m01);
        const __half2 mh11 = __float2half2_rn(m11);
        __half2 hz = __floats2half2_rn(0.0f, 0.0f);
        __half2 a0 = hz, a1 = hz, a2 = hz, a3 = hz, a4 = hz, a5 = hz;
        #define BLENDH(Av, Cv, mh) {            \
            a0 = __hfma2(mh, bc2(Av.x), a0);    \
            a1 = __hfma2(mh, bc2(Av.y), a1);    \
            a2 = __hfma2(mh, bc2(Av.z), a2);    \
            a3 = __hfma2(mh, bc2(Av.w), a3);    \
            a4 = __hfma2(mh, bc2(Cv.x), a4);    \
            a5 = __hfma2(mh, bc2(Cv.y), a5); }
        BLENDH(A00, C00, mh00)
        BLENDH(A10, C10, mh10)
        BLENDH(A01, C01, mh01)
        BLENDH(A11, C11, mh11)
        #undef BLENDH
        const float2 f0 = h2f(a0), f1 = h2f(a1), f2 = h2f(a2),
                     f3 = h2f(a3), f4 = h2f(a4), f5 = h2f(a5);
        const float sv0 = f0.x, sv1 = f0.y, sv2 = f1.x, sv3 = f1.y;
        const float gx0 = f2.x, gx1 = f2.y, gx2 = f3.x, gx3 = f3.y;
        const float gy0 = f4.x, gy1 = f4.y, gy2 = f5.x, gy3 = f5.y;

        // ---- factorized accumulate: S (3x3 sym) and u over 4 channels ----
        float S00=0,S01=0,S02=0,S11=0,S12=0,S22=0, U0=0,U1=0,U2=0;
        #define PHOTO(SVc, GXc, GYc, P1c) {                            \
            const float r  = vm ? (P1c - SVc) : 1e-6f;                 \
            const float w  = fminf(1.0f, HUBER_*frcp(fmaxf(fabsf(r), EPS_))); \
            const float hx = GXc*aJ, hy = GYc*bJ, hz_ = GXc*cJ + GYc*dJ;  \
            const float whx = w*hx, why = w*hy, wr = w*r;              \
            S00 += whx*hx; S01 += whx*hy; S02 += whx*hz_;              \
            S11 += why*hy; S12 += why*hz_; S22 += w*hz_*hz_;           \
            U0 -= wr*hx; U1 -= wr*hy; U2 -= wr*hz_; }
        PHOTO(sv0, gx0, gy0, p1a)
        PHOTO(sv1, gx1, gy1, p1b)
        PHOTO(sv2, gx2, gy2, p1c)
        #undef PHOTO
        {   // depth channel: J = LAMBDA*(e3 - h_d)*Jt
            const float rz = LAMBDA_*(vm ? (izc - sv3) : 1e-6f);
            const float w  = fminf(1.0f, HUBER_*frcp(fmaxf(fabsf(rz), EPS_)));
            const float hx = gx3*aJ, hy = gy3*bJ, hz_ = gx3*cJ + gy3*dJ;
            const float qx = -hx, qy = -hy, qz = 1.0f - hz_;
            const float wl2 = w*(LAMBDA_*LAMBDA_);
            const float wqx = wl2*qx, wqy = wl2*qy;
            S00 += wqx*qx; S01 += wqx*qy; S02 += wqx*qz;
            S11 += wqy*qy; S12 += wqy*qz; S22 += wl2*qz*qz;
            const float wrl = w*rz*LAMBDA_;
            U0 += wrl*qx; U1 += wrl*qy; U2 += wrl*qz;
        }
        // expand via Jt = [I | -K], K = skew(Xi): M=[[S,-SK],[.,K'SK]]
        const float x = Xi0, y = Xi1, z = Xi2;
        const float P00 =  S01*z - S02*y, P01 = -S00*z + S02*x, P02 =  S00*y - S01*x;
        const float P10 =  S11*z - S12*y, P11 = -S01*z + S12*x, P12 =  S01*y - S11*x;
        const float P20 =  S12*z - S22*y, P21 = -S02*z + S22*x, P22 =  S02*y - S12*x;
        const float Q00 =  z*P10 - y*P20, Q01 =  z*P11 - y*P21, Q02 =  z*P12 - y*P22;
        const float Q11 = -z*P01 + x*P21, Q12 = -z*P02 + x*P22;
        const float Q22 =  y*P02 - x*P12;
        acc[0]  += S00; acc[1]  += S01; acc[2]  += S02;
        acc[3]  += S11; acc[4]  += S12; acc[5]  += S22;
        acc[6]  -= P00; acc[7]  -= P01; acc[8]  -= P02;
        acc[9]  -= P10; acc[10] -= P11; acc[11] -= P12;
        acc[12] -= P20; acc[13] -= P21; acc[14] -= P22;
        acc[15] += Q00; acc[16] += Q01; acc[17] += Q02;
        acc[18] += Q11; acc[19] += Q12; acc[20] += Q22;
        acc[21] += U0; acc[22] += U1; acc[23] += U2;
        acc[24] += y*U2 - z*U1;
        acc[25] += z*U0 - x*U2;
        acc[26] += x*U1 - y*U0;
    };

    #pragma unroll
    for (int i5 = 0; i5 < PPT; ++i5)
        body(i5);

    // wave (64-lane) reduction in float
    #pragma unroll
    for (int off = 32; off >= 1; off >>= 1) {
        #pragma unroll
        for (int k = 0; k < 27; ++k)
            acc[k] += __shfl_down(acc[k], off);
    }
    __shared__ float red[TPB/64][27];
    const int lane = threadIdx.x & 63;
    const int wid  = threadIdx.x >> 6;
    if (lane == 0) {
        #pragma unroll
        for (int k = 0; k < 27; ++k) red[wid][k] = acc[k];
    }
    __syncthreads();
    if (threadIdx.x < 27) {
        float s = red[0][threadIdx.x] + red[1][threadIdx.x]
                + red[2][threadIdx.x] + red[3][threadIdx.x];
        partials[((size_t)b*BPB + blk)*27 + threadIdx.x] = s;
    }
}

// ---------------- reduce partials, solve 6x6, update T ----------------
// partials layout: 0-5 S upper; 6-14 topright 3x3 row-major; 15-20 BR upper;
// 21-26 rhs.
__global__ void solve_kernel(const float* __restrict__ partials,
                             float* __restrict__ Tcur, float* __restrict__ out)
{
    const int b = blockIdx.x;
    __shared__ double S[27];
    const int t = threadIdx.x;
    if (t < 27) {
        double s = 0.0;
        const float* pp = partials + (size_t)b*BPB*27 + t;
        for (int blk = 0; blk < BPB; ++blk) s += (double)pp[blk*27];
        S[t] = s;
    }
    __syncthreads();
    if (t == 0) {
        double Hm[6][6], rhs[6];
        Hm[0][0]=S[0];  Hm[0][1]=S[1];  Hm[0][2]=S[2];
        Hm[1][1]=S[3];  Hm[1][2]=S[4];  Hm[2][2]=S[5];
        for (int i = 0; i < 3; ++i)
            for (int j = 0; j < 3; ++j)
                Hm[i][3+j] = S[6 + i*3 + j];
        Hm[3][3]=S[15]; Hm[3][4]=S[16]; Hm[3][5]=S[17];
        Hm[4][4]=S[18]; Hm[4][5]=S[19]; Hm[5][5]=S[20];
        for (int i = 0; i < 6; ++i)
            for (int j = 0; j < i; ++j) Hm[i][j] = Hm[j][i];
        for (int i = 0; i < 6; ++i) rhs[i] = S[21+i];

        double tr = 0.0;
        for (int i = 0; i < 6; ++i) tr += Hm[i][i];
        const double damp = tr*1e-6;
        for (int i = 0; i < 6; ++i) Hm[i][i] += damp;

        double M[6][7];
        for (int i = 0; i < 6; ++i) {
            for (int j = 0; j < 6; ++j) M[i][j] = Hm[i][j];
            M[i][6] = rhs[i];
        }
        for (int col = 0; col < 6; ++col) {
            int piv = col; double mx = fabs(M[col][col]);
            for (int r2 = col+1; r2 < 6; ++r2) {
                double a2 = fabs(M[r2][col]);
                if (a2 > mx) { mx = a2; piv = r2; }
            }
            if (piv != col)
                for (int j = col; j < 7; ++j) {
                    double tmp = M[col][j]; M[col][j] = M[piv][j]; M[piv][j] = tmp;
                }
            const double inv = 1.0 / M[col][col];
            for (int r2 = col+1; r2 < 6; ++r2) {
                const double f = M[r2][col]*inv;
                for (int j = col; j < 7; ++j) M[r2][j] -= f*M[col][j];
            }
        }
        double xi[6];
        for (int i = 5; i >= 0; --i) {
            double s2 = M[i][6];
            for (int j = i+1; j < 6; ++j) s2 -= M[i][j]*xi[j];
            xi[i] = s2 / M[i][i];
        }
        double nxi[6];
        for (int i = 0; i < 6; ++i) nxi[i] = -xi[i];
        double E[16];
        se3_exp_d(nxi, E);

        double Tc[16];
        for (int k = 0; k < 16; ++k) Tc[k] = (double)Tcur[b*16+k];
        for (int i = 0; i < 4; ++i)
            for (int j = 0; j < 4; ++j) {
                double s2 = 0.0;
                for (int k = 0; k < 4; ++k) s2 += Tc[i*4+k]*E[k*4+j];
                const float f = (float)s2;
                Tcur[b*16 + i*4 + j] = f;
                out[b*16 + i*4 + j]  = f;
            }
    }
}

extern "C" void kernel_launch(void* const* d_in, const int* in_sizes, int n_in,
                              void* d_out, int out_size, void* d_ws, size_t ws_size,
                              hipStream_t stream) {
    const float* pose  = (const float*)d_in[0];
    const float* I0    = (const float*)d_in[1];
    const float* I1    = (const float*)d_in[2];
    const float* invD0 = (const float*)d_in[3];
    const float* invD1 = (const float*)d_in[4];
    const float* intr  = (const float*)d_in[5];
    float* out = (float*)d_out;

    float* Tcur     = (float*)d_ws;
    float* Tinit    = Tcur + 256;
    float* partials = (float*)((char*)d_ws + PARTIALS_OFF);
    uint2* P2       = (uint2*)((char*)d_ws + PLANE_OFF);

    hipLaunchKernelGGL(init_kernel, dim3(1), dim3(64), 0, stream, pose, Tcur, Tinit);
    hipLaunchKernelGGL(pack_kernel, dim3(B_*PRE_BPB), dim3(TPB), 0, stream,
                       I0, invD0, P2);
    for (int it = 0; it < NITERS_; ++it) {
        hipLaunchKernelGGL(pixel_h16_kernel, dim3(B_*BPB), dim3(TPB), 0, stream,
                           P2, I1, invD1, intr, Tcur, Tinit, partials);
        hipLaunchKernelGGL(solve_kernel, dim3(B_), dim3(64), 0, stream,
                           partials, Tcur, out);
    }
}

// Round 15
// 274.526 us; speedup vs baseline: 1.0548x; 1.0548x over previous
//
#include <hip/hip_runtime.h>
#include <hip/hip_fp16.h>
#include <math.h>

#define B_ 16
#define C_ 3
#define H_ 320
#define W_ 448
#define HW_ (H_*W_)
#define NITERS_ 5
#define LAMBDA_ 0.01f
#define HUBER_ 0.1f
#define EPS_ 1e-6f

#define BPB 112       // blocks per batch (1792 total) -- proven shape
#define CHUNK 1280    // pixels per block == 5*TPB; 112*1280 == H*W
#define TPB 256
#define PPT 5

// workspace layout
#define PARTIALS_OFF 2048
#define PLANE_OFF    262144
#define PLANE_U4     ((size_t)B_*HW_)              // uint4 elements (16B/px)
#define WS_NEED      (PLANE_OFF + PLANE_U4*16)     // ~37 MB (ws>=110MB proven R5)

typedef __attribute__((__vector_size__(2 * sizeof(float)))) float vfloat2;

// ---------------- SE(3) exp in double ----------------
__device__ __host__ inline void se3_exp_d(const double xi[6], double T[16]) {
    double vx = xi[0], vy = xi[1], vz = xi[2];
    double wx = xi[3], wy = xi[4], wz = xi[5];
    double th2  = wx*wx + wy*wy + wz*wz;
    double th2c = th2 > 1e-16 ? th2 : 1e-16;
    double th   = sqrt(th2c);
    bool   sm   = th2 < 1e-10;
    double A  = sm ? (1.0 - th2*(1.0/6.0))   : (sin(th)/th);
    double Bc = sm ? (0.5 - th2*(1.0/24.0))  : ((1.0 - cos(th))/th2c);
    double Cc = sm ? (1.0/6.0 - th2*(1.0/120.0)) : ((1.0 - A)/th2c);
    double K[9]  = {0.0,-wz,wy,  wz,0.0,-wx,  -wy,wx,0.0};
    double K2[9];
    #pragma unroll
    for (int i = 0; i < 3; ++i)
        #pragma unroll
        for (int j = 0; j < 3; ++j) {
            double s = 0.0;
            #pragma unroll
            for (int k = 0; k < 3; ++k) s += K[i*3+k]*K[k*3+j];
            K2[i*3+j] = s;
        }
    double R[9], V[9];
    #pragma unroll
    for (int i = 0; i < 9; ++i) {
        double I = (i == 0 || i == 4 || i == 8) ? 1.0 : 0.0;
        R[i] = I + A*K[i]  + Bc*K2[i];
        V[i] = I + Bc*K[i] + Cc*K2[i];
    }
    double tx = V[0]*vx + V[1]*vy + V[2]*vz;
    double ty = V[3]*vx + V[4]*vy + V[5]*vz;
    double tz = V[6]*vx + V[7]*vy + V[8]*vz;
    T[0]=R[0]; T[1]=R[1]; T[2] =R[2]; T[3] =tx;
    T[4]=R[3]; T[5]=R[4]; T[6] =R[5]; T[7] =ty;
    T[8]=R[6]; T[9]=R[7]; T[10]=R[8]; T[11]=tz;
    T[12]=0.0; T[13]=0.0; T[14]=0.0;  T[15]=1.0;
}

// ---------------- init: T = se3_exp(pose_twist) ----------------
__global__ void init_kernel(const float* __restrict__ pose,
                            float* __restrict__ Tcur, float* __restrict__ Tinit) {
    int b = threadIdx.x;
    if (b >= B_) return;
    double xi[6];
    #pragma unroll
    for (int k = 0; k < 6; ++k) xi[k] = (double)pose[b*6+k];
    double T[16];
    se3_exp_d(xi, T);
    #pragma unroll
    for (int k = 0; k < 16; ++k) {
        float f = (float)T[k];
        Tcur[b*16+k]  = f;
        Tinit[b*16+k] = f;
    }
}

// ---------------- precompute: 16B/px plane -----------------------------
// .x,.y = v.rgbd (4 x fp16); .z = dx.rgbd (4 x fp8 e4m3); .w = dy.rgbd.
#define PRE_BPB (HW_/TPB)   // 560
__device__ __forceinline__ unsigned pk16(float a, float b) {
    __half2 h = __floats2half2_rn(a, b);
    unsigned u; __builtin_memcpy(&u, &h, 4); return u;
}
__global__ __launch_bounds__(TPB)
void pack_kernel(const float* __restrict__ I0, const float* __restrict__ invD0,
                 uint4* __restrict__ P4)
{
    const int b   = blockIdx.x / PRE_BPB;
    const int rem = blockIdx.x % PRE_BPB;
    const int p   = rem*TPB + (int)threadIdx.x;
    const int y   = p / W_;
    const int x   = p - y*W_;
    const int xp  = (x < W_-1) ? 1 : 0;
    const int xm  = (x > 0) ? -1 : 0;
    const int yp  = (y < H_-1) ? W_ : 0;
    const int ym  = (y > 0) ? -W_ : 0;

    const float* s0 = I0    + (size_t)b*C_*HW_ + p;
    const float* sd = invD0 + (size_t)b*HW_   + p;

    const float v0 = s0[0], v1 = s0[HW_], v2 = s0[2*HW_], v3 = sd[0];
    const float dx0 = 0.5f*(s0[xp]       - s0[xm]);
    const float dx1 = 0.5f*(s0[HW_+xp]   - s0[HW_+xm]);
    const float dx2 = 0.5f*(s0[2*HW_+xp] - s0[2*HW_+xm]);
    const float dx3 = 0.5f*(sd[xp]       - sd[xm]);
    const float dy0 = 0.5f*(s0[yp]       - s0[ym]);
    const float dy1 = 0.5f*(s0[HW_+yp]   - s0[HW_+ym]);
    const float dy2 = 0.5f*(s0[2*HW_+yp] - s0[2*HW_+ym]);
    const float dy3 = 0.5f*(sd[yp]       - sd[ym]);

    int zx = 0, zy = 0;
    zx = __builtin_amdgcn_cvt_pk_fp8_f32(dx0, dx1, zx, false);
    zx = __builtin_amdgcn_cvt_pk_fp8_f32(dx2, dx3, zx, true);
    zy = __builtin_amdgcn_cvt_pk_fp8_f32(dy0, dy1, zy, false);
    zy = __builtin_amdgcn_cvt_pk_fp8_f32(dy2, dy3, zy, true);

    P4[(size_t)b*HW_ + p] = make_uint4(pk16(v0,v1), pk16(v2,v3),
                                       (unsigned)zx, (unsigned)zy);
}

__device__ __forceinline__ __half2 bc2(unsigned u) {
    __half2 h; __builtin_memcpy(&h, &u, 4); return h;
}
__device__ __forceinline__ float2 h2f(__half2 h) { return __half22float2(h); }

// ---------------- per-pixel GN accumulation (16B plane, 4 loads/px) ------
// R12 structure, gather halved again: ONE uint4 load per tap (4/px vs R12's
// 8). Values fp16, gradients fp8-e4m3 (zero-mean quantization noise on J ->
// GN fixed point unmoved; same contraction argument as R12's fp16 = 0.0).
// NO launch_bounds min-waves (R2/R3/R6 spill history).
__global__ __launch_bounds__(TPB)
void pixel_h8_kernel(const uint4* __restrict__ P4,
                     const float* __restrict__ I1, const float* __restrict__ invD1,
                     const float* __restrict__ intr,
                     const float* __restrict__ Tcur, const float* __restrict__ Tinit,
                     float* __restrict__ partials)
{
    // XCD-aware swizzle (bijective, 1792 % 8 == 0): contiguous chunks per XCD.
    const int nwg = B_*BPB;
    const int bid = blockIdx.x;
    const int swz = (bid & 7) * (nwg >> 3) + (bid >> 3);
    const int b   = swz / BPB;
    const int blk = swz % BPB;

    const float fx = intr[b*4+0], fy = intr[b*4+1];
    const float cx = intr[b*4+2], cy = intr[b*4+3];
    const float inv_fx = 1.0f/fx, inv_fy = 1.0f/fy;

    const float* Tc = Tcur  + b*16;
    const float* Ti = Tinit + b*16;
    const float Rc00=Tc[0], Rc01=Tc[1], Rc02=Tc[2],  tcx=Tc[3];
    const float Rc10=Tc[4], Rc11=Tc[5], Rc12=Tc[6],  tcy=Tc[7];
    const float Rc20=Tc[8], Rc21=Tc[9], Rc22=Tc[10], tcz=Tc[11];
    const float Ri00=Ti[0], Ri01=Ti[1], Ri02=Ti[2],  tix=Ti[3];
    const float Ri10=Ti[4], Ri11=Ti[5], Ri12=Ti[6],  tiy=Ti[7];
    const float Ri20=Ti[8], Ri21=Ti[9], Ri22=Ti[10], tiz=Ti[11];

    const uint4* Pb = P4 + (size_t)b*HW_;
    const float* P1 = I1    + (size_t)b*C_*HW_;
    const float* D1 = invD1 + (size_t)b*HW_;

    float acc[27];
    #pragma unroll
    for (int k = 0; k < 27; ++k) acc[k] = 0.0f;

    const int base = blk*CHUNK + (int)threadIdx.x;

    // d1 preload (protects each body's serial front head)
    float d1v[PPT];
    #pragma unroll
    for (int i = 0; i < PPT; ++i) d1v[i] = D1[base + i*TPB];

    auto body = [&](int i5) {
        const int p = base + i5*TPB;
        const int vcoord = p / W_;
        const int ucoord = p - vcoord*W_;

        // P1 loads issue first -- independent, overlap the gather wait
        const float p1a = P1[p];
        const float p1b = P1[HW_ + p];
        const float p1c = P1[2*HW_ + p];

        const float iD1 = d1v[i5];
        const float iD  = fmaxf(iD1, EPS_);
        const float z1  = 1.0f / iD;
        const float x1  = ((float)ucoord - cx)*inv_fx * z1;
        const float y1  = ((float)vcoord - cy)*inv_fy * z1;

        // current warp
        const float Xc0 = Rc00*x1 + Rc01*y1 + Rc02*z1 + tcx;
        const float Xc1 = Rc10*x1 + Rc11*y1 + Rc12*z1 + tcy;
        const float Xc2 = Rc20*x1 + Rc21*y1 + Rc22*z1 + tcz;
        const float z0s = (fabsf(Xc2) > EPS_) ? Xc2 : EPS_;
        const float izc = 1.0f / z0s;
        const float u0  = fx*Xc0*izc + cx;
        const float v0  = fy*Xc1*izc + cy;
        const bool valid = (Xc2 > EPS_) && (iD1 > EPS_);
        const bool inb   = (u0 > 0.0f) && (u0 < (float)(W_-1)) &&
                           (v0 > 0.0f) && (v0 < (float)(H_-1));
        const bool vm = valid && inb;

        // initial-T projection for Jacobian (fixed linearization point)
        const float Xi0 = Ri00*x1 + Ri01*y1 + Ri02*z1 + tix;
        const float Xi1 = Ri10*x1 + Ri11*y1 + Ri12*z1 + tiy;
        const float Xi2 = Ri20*x1 + Ri21*y1 + Ri22*z1 + tiz;
        const float zis = (fabsf(Xi2) > EPS_) ? Xi2 : EPS_;
        const float izi = 1.0f / zis;
        const float aJ = fx*izi;
        const float cJ = -fx*Xi0*izi*izi;
        const float bJ = fy*izi;
        const float dJ = -fy*Xi1*izi*izi;

        // normalized grid (clipped), back to pixel coords -- mirror reference
        const float gx = fminf(fmaxf((u0/(float)(W_-1) - 0.5f)*2.0f, -2.0f), 2.0f);
        const float gy = fminf(fmaxf((v0/(float)(H_-1) - 0.5f)*2.0f, -2.0f), 2.0f);
        const float ix = (gx + 1.0f)*0.5f*(float)(W_-1);
        const float iy = (gy + 1.0f)*0.5f*(float)(H_-1);
        const float x0f = floorf(ix), y0f = floorf(iy);
        const float wx1 = ix - x0f,  wy1 = iy - y0f;
        const float wx0 = 1.0f - wx1, wy0 = 1.0f - wy1;

        // per-tap masks (reference: tap inside [0,W-1]x[0,H-1])
        const bool bx0 = (x0f >= 0.0f)  && (x0f <= (float)(W_-1));
        const bool bx1 = (x0f >= -1.0f) && (x0f <= (float)(W_-2));
        const bool by0 = (y0f >= 0.0f)  && (y0f <= (float)(H_-1));
        const bool by1 = (y0f >= -1.0f) && (y0f <= (float)(H_-2));
        const float m00 = (bx0 && by0) ? wx0*wy0 : 0.0f;
        const float m10 = (bx1 && by0) ? wx1*wy0 : 0.0f;
        const float m01 = (bx0 && by1) ? wx0*wy1 : 0.0f;
        const float m11 = (bx1 && by1) ? wx1*wy1 : 0.0f;

        const int x0i = (int)x0f;
        const int y0i = (int)y0f;
        const int c0 = min(max(x0i,   0), W_-1);
        const int c1 = min(max(x0i+1, 0), W_-1);
        const int o0 = min(max(y0i,   0), H_-1) * W_;
        const int o1 = min(max(y0i+1, 0), H_-1) * W_;

        // single gather batch: 4 x uint4 (one load per tap)
        const uint4 A00 = Pb[o0+c0];
        const uint4 A10 = Pb[o0+c1];
        const uint4 A01 = Pb[o1+c0];
        const uint4 A11 = Pb[o1+c1];

        float sv0=0,sv1=0,sv2=0,sv3=0;
        float gx0=0,gx1=0,gx2=0,gx3=0;
        float gy0=0,gy1=0,gy2=0,gy3=0;
        #define BLEND(A, m) {                                               \
            float2 t;                                                       \
            t = h2f(bc2(A.x)); sv0 += m*t.x; sv1 += m*t.y;                  \
            t = h2f(bc2(A.y)); sv2 += m*t.x; sv3 += m*t.y;                  \
            vfloat2 g0 = __builtin_amdgcn_cvt_pk_f32_fp8((int)A.z, false);  \
            gx0 += m*g0[0]; gx1 += m*g0[1];                                 \
            vfloat2 g1 = __builtin_amdgcn_cvt_pk_f32_fp8((int)A.z, true);   \
            gx2 += m*g1[0]; gx3 += m*g1[1];                                 \
            vfloat2 g2 = __builtin_amdgcn_cvt_pk_f32_fp8((int)A.w, false);  \
            gy0 += m*g2[0]; gy1 += m*g2[1];                                 \
            vfloat2 g3 = __builtin_amdgcn_cvt_pk_f32_fp8((int)A.w, true);   \
            gy2 += m*g3[0]; gy3 += m*g3[1]; }
        BLEND(A00, m00)
        BLEND(A10, m10)
        BLEND(A01, m01)
        BLEND(A11, m11)
        #undef BLEND

        // ---- factorized accumulate: S (3x3 sym) and u over 4 channels ----
        float S00=0,S01=0,S02=0,S11=0,S12=0,S22=0, U0=0,U1=0,U2=0;
        #define PHOTO(SVc, GXc, GYc, P1c) {                            \
            const float r  = vm ? (P1c - SVc) : 1e-6f;                 \
            const float w  = fminf(1.0f, HUBER_ / fmaxf(fabsf(r), EPS_)); \
            const float hx = GXc*aJ, hy = GYc*bJ, hz_ = GXc*cJ + GYc*dJ;  \
            const float whx = w*hx, why = w*hy, wr = w*r;              \
            S00 += whx*hx; S01 += whx*hy; S02 += whx*hz_;              \
            S11 += why*hy; S12 += why*hz_; S22 += w*hz_*hz_;           \
            U0 -= wr*hx; U1 -= wr*hy; U2 -= wr*hz_; }
        PHOTO(sv0, gx0, gy0, p1a)
        PHOTO(sv1, gx1, gy1, p1b)
        PHOTO(sv2, gx2, gy2, p1c)
        #undef PHOTO
        {   // depth channel: J = LAMBDA*(e3 - h_d)*Jt
            const float rz = LAMBDA_*(vm ? (izc - sv3) : 1e-6f);
            const float w  = fminf(1.0f, HUBER_ / fmaxf(fabsf(rz), EPS_));
            const float hx = gx3*aJ, hy = gy3*bJ, hz_ = gx3*cJ + gy3*dJ;
            const float qx = -hx, qy = -hy, qz = 1.0f - hz_;
            const float wl2 = w*(LAMBDA_*LAMBDA_);
            const float wqx = wl2*qx, wqy = wl2*qy;
            S00 += wqx*qx; S01 += wqx*qy; S02 += wqx*qz;
            S11 += wqy*qy; S12 += wqy*qz; S22 += wl2*qz*qz;
            const float wrl = w*rz*LAMBDA_;
            U0 += wrl*qx; U1 += wrl*qy; U2 += wrl*qz;
        }
        // expand via Jt = [I | -K], K = skew(Xi): M=[[S,-SK],[.,K'SK]]
        const float x = Xi0, y = Xi1, z = Xi2;
        const float P00 =  S01*z - S02*y, P01 = -S00*z + S02*x, P02 =  S00*y - S01*x;
        const float P10 =  S11*z - S12*y, P11 = -S01*z + S12*x, P12 =  S01*y - S11*x;
        const float P20 =  S12*z - S22*y, P21 = -S02*z + S22*x, P22 =  S02*y - S12*x;
        const float Q00 =  z*P10 - y*P20, Q01 =  z*P11 - y*P21, Q02 =  z*P12 - y*P22;
        const float Q11 = -z*P01 + x*P21, Q12 = -z*P02 + x*P22;
        const float Q22 =  y*P02 - x*P12;
        acc[0]  += S00; acc[1]  += S01; acc[2]  += S02;
        acc[3]  += S11; acc[4]  += S12; acc[5]  += S22;
        acc[6]  -= P00; acc[7]  -= P01; acc[8]  -= P02;
        acc[9]  -= P10; acc[10] -= P11; acc[11] -= P12;
        acc[12] -= P20; acc[13] -= P21; acc[14] -= P22;
        acc[15] += Q00; acc[16] += Q01; acc[17] += Q02;
        acc[18] += Q11; acc[19] += Q12; acc[20] += Q22;
        acc[21] += U0; acc[22] += U1; acc[23] += U2;
        acc[24] += y*U2 - z*U1;
        acc[25] += z*U0 - x*U2;
        acc[26] += x*U1 - y*U0;
    };

    #pragma unroll
    for (int i5 = 0; i5 < PPT; ++i5)
        body(i5);

    // wave (64-lane) reduction in float
    #pragma unroll
    for (int off = 32; off >= 1; off >>= 1) {
        #pragma unroll
        for (int k = 0; k < 27; ++k)
            acc[k] += __shfl_down(acc[k], off);
    }
    __shared__ float red[TPB/64][27];
    const int lane = threadIdx.x & 63;
    const int wid  = threadIdx.x >> 6;
    if (lane == 0) {
        #pragma unroll
        for (int k = 0; k < 27; ++k) red[wid][k] = acc[k];
    }
    __syncthreads();
    if (threadIdx.x < 27) {
        float s = red[0][threadIdx.x] + red[1][threadIdx.x]
                + red[2][threadIdx.x] + red[3][threadIdx.x];
        partials[((size_t)b*BPB + blk)*27 + threadIdx.x] = s;
    }
}

// ---------------- reduce partials, solve 6x6, update T ----------------
// partials layout: 0-5 S upper; 6-14 topright 3x3 row-major; 15-20 BR upper;
// 21-26 rhs.
__global__ void solve_kernel(const float* __restrict__ partials,
                             float* __restrict__ Tcur, float* __restrict__ out)
{
    const int b = blockIdx.x;
    __shared__ double S[27];
    const int t = threadIdx.x;
    if (t < 27) {
        double s = 0.0;
        const float* pp = partials + (size_t)b*BPB*27 + t;
        for (int blk = 0; blk < BPB; ++blk) s += (double)pp[blk*27];
        S[t] = s;
    }
    __syncthreads();
    if (t == 0) {
        double Hm[6][6], rhs[6];
        Hm[0][0]=S[0];  Hm[0][1]=S[1];  Hm[0][2]=S[2];
        Hm[1][1]=S[3];  Hm[1][2]=S[4];  Hm[2][2]=S[5];
        for (int i = 0; i < 3; ++i)
            for (int j = 0; j < 3; ++j)
                Hm[i][3+j] = S[6 + i*3 + j];
        Hm[3][3]=S[15]; Hm[3][4]=S[16]; Hm[3][5]=S[17];
        Hm[4][4]=S[18]; Hm[4][5]=S[19]; Hm[5][5]=S[20];
        for (int i = 0; i < 6; ++i)
            for (int j = 0; j < i; ++j) Hm[i][j] = Hm[j][i];
        for (int i = 0; i < 6; ++i) rhs[i] = S[21+i];

        double tr = 0.0;
        for (int i = 0; i < 6; ++i) tr += Hm[i][i];
        const double damp = tr*1e-6;
        for (int i = 0; i < 6; ++i) Hm[i][i] += damp;

        double M[6][7];
        for (int i = 0; i < 6; ++i) {
            for (int j = 0; j < 6; ++j) M[i][j] = Hm[i][j];
            M[i][6] = rhs[i];
        }
        for (int col = 0; col < 6; ++col) {
            int piv = col; double mx = fabs(M[col][col]);
            for (int r2 = col+1; r2 < 6; ++r2) {
                double a2 = fabs(M[r2][col]);
                if (a2 > mx) { mx = a2; piv = r2; }
            }
            if (piv != col)
                for (int j = col; j < 7; ++j) {
                    double tmp = M[col][j]; M[col][j] = M[piv][j]; M[piv][j] = tmp;
                }
            const double inv = 1.0 / M[col][col];
            for (int r2 = col+1; r2 < 6; ++r2) {
                const double f = M[r2][col]*inv;
                for (int j = col; j < 7; ++j) M[r2][j] -= f*M[col][j];
            }
        }
        double xi[6];
        for (int i = 5; i >= 0; --i) {
            double s2 = M[i][6];
            for (int j = i+1; j < 6; ++j) s2 -= M[i][j]*xi[j];
            xi[i] = s2 / M[i][i];
        }
        double nxi[6];
        for (int i = 0; i < 6; ++i) nxi[i] = -xi[i];
        double E[16];
        se3_exp_d(nxi, E);

        double Tc[16];
        for (int k = 0; k < 16; ++k) Tc[k] = (double)Tcur[b*16+k];
        for (int i = 0; i < 4; ++i)
            for (int j = 0; j < 4; ++j) {
                double s2 = 0.0;
                for (int k = 0; k < 4; ++k) s2 += Tc[i*4+k]*E[k*4+j];
                const float f = (float)s2;
                Tcur[b*16 + i*4 + j] = f;
                out[b*16 + i*4 + j]  = f;
            }
    }
}

extern "C" void kernel_launch(void* const* d_in, const int* in_sizes, int n_in,
                              void* d_out, int out_size, void* d_ws, size_t ws_size,
                              hipStream_t stream) {
    const float* pose  = (const float*)d_in[0];
    const float* I0    = (const float*)d_in[1];
    const float* I1    = (const float*)d_in[2];
    const float* invD0 = (const float*)d_in[3];
    const float* invD1 = (const float*)d_in[4];
    const float* intr  = (const float*)d_in[5];
    float* out = (float*)d_out;

    float* Tcur     = (float*)d_ws;
    float* Tinit    = Tcur + 256;
    float* partials = (float*)((char*)d_ws + PARTIALS_OFF);
    uint4* P4       = (uint4*)((char*)d_ws + PLANE_OFF);

    hipLaunchKernelGGL(init_kernel, dim3(1), dim3(64), 0, stream, pose, Tcur, Tinit);
    hipLaunchKernelGGL(pack_kernel, dim3(B_*PRE_BPB), dim3(TPB), 0, stream,
                       I0, invD0, P4);
    for (int it = 0; it < NITERS_; ++it) {
        hipLaunchKernelGGL(pixel_h8_kernel, dim3(B_*BPB), dim3(TPB), 0, stream,
                           P4, I1, invD1, intr, Tcur, Tinit, partials);
        hipLaunchKernelGGL(solve_kernel, dim3(B_), dim3(64), 0, stream,
                           partials, Tcur, out);
    }
}

// Round 16
// 268.397 us; speedup vs baseline: 1.0789x; 1.0228x over previous
//
#include <hip/hip_runtime.h>
#include <hip/hip_fp16.h>
#include <math.h>

#define B_ 16
#define C_ 3
#define H_ 320
#define W_ 448
#define HW_ (H_*W_)
#define NITERS_ 5
#define LAMBDA_ 0.01f
#define HUBER_ 0.1f
#define EPS_ 1e-6f

#define BPB 112       // blocks per batch (1792 total) -- proven shape
#define CHUNK 1280    // pixels per block == 5*TPB; 112*1280 == H*W
#define TPB 256
#define PPT 5

// workspace layout
#define PARTIALS_OFF 2048            // 16*112*27*4 ~ 189KB, ends < 200KB
#define DMAT_OFF     200704          // 16 batches x 12 floats
#define PLANE_OFF    262144
#define PLANE_U4     ((size_t)B_*HW_)              // uint4 elements (16B/px)
#define XI_OFF       (PLANE_OFF + PLANE_U4*16)     // float4 Xi plane (16B/px)
// total ~73.6MB < proven-available 110MB

typedef __attribute__((__vector_size__(2 * sizeof(float)))) float vfloat2;

// ---------------- SE(3) exp in double ----------------
__device__ __host__ inline void se3_exp_d(const double xi[6], double T[16]) {
    double vx = xi[0], vy = xi[1], vz = xi[2];
    double wx = xi[3], wy = xi[4], wz = xi[5];
    double th2  = wx*wx + wy*wy + wz*wz;
    double th2c = th2 > 1e-16 ? th2 : 1e-16;
    double th   = sqrt(th2c);
    bool   sm   = th2 < 1e-10;
    double A  = sm ? (1.0 - th2*(1.0/6.0))   : (sin(th)/th);
    double Bc = sm ? (0.5 - th2*(1.0/24.0))  : ((1.0 - cos(th))/th2c);
    double Cc = sm ? (1.0/6.0 - th2*(1.0/120.0)) : ((1.0 - A)/th2c);
    double K[9]  = {0.0,-wz,wy,  wz,0.0,-wx,  -wy,wx,0.0};
    double K2[9];
    #pragma unroll
    for (int i = 0; i < 3; ++i)
        #pragma unroll
        for (int j = 0; j < 3; ++j) {
            double s = 0.0;
            #pragma unroll
            for (int k = 0; k < 3; ++k) s += K[i*3+k]*K[k*3+j];
            K2[i*3+j] = s;
        }
    double R[9], V[9];
    #pragma unroll
    for (int i = 0; i < 9; ++i) {
        double I = (i == 0 || i == 4 || i == 8) ? 1.0 : 0.0;
        R[i] = I + A*K[i]  + Bc*K2[i];
        V[i] = I + Bc*K[i] + Cc*K2[i];
    }
    double tx = V[0]*vx + V[1]*vy + V[2]*vz;
    double ty = V[3]*vx + V[4]*vy + V[5]*vz;
    double tz = V[6]*vx + V[7]*vy + V[8]*vz;
    T[0]=R[0]; T[1]=R[1]; T[2] =R[2]; T[3] =tx;
    T[4]=R[3]; T[5]=R[4]; T[6] =R[5]; T[7] =ty;
    T[8]=R[6]; T[9]=R[7]; T[10]=R[8]; T[11]=tz;
    T[12]=0.0; T[13]=0.0; T[14]=0.0;  T[15]=1.0;
}

// D = Rcur * Rinit^T ; d = tcur - D * tinit   (all double, stored float)
__device__ inline void write_delta(const double Tc[16], const float* Ti,
                                   float* Dm) {
    double Ri[9], ti[3];
    Ri[0]=Ti[0]; Ri[1]=Ti[1]; Ri[2]=Ti[2];  ti[0]=Ti[3];
    Ri[3]=Ti[4]; Ri[4]=Ti[5]; Ri[5]=Ti[6];  ti[1]=Ti[7];
    Ri[6]=Ti[8]; Ri[7]=Ti[9]; Ri[8]=Ti[10]; ti[2]=Ti[11];
    double D[9];
    #pragma unroll
    for (int i = 0; i < 3; ++i)
        #pragma unroll
        for (int j = 0; j < 3; ++j)
            D[i*3+j] = Tc[i*4+0]*Ri[j*3+0] + Tc[i*4+1]*Ri[j*3+1] + Tc[i*4+2]*Ri[j*3+2];
    #pragma unroll
    for (int i = 0; i < 3; ++i) {
        const double di = Tc[i*4+3] - (D[i*3+0]*ti[0] + D[i*3+1]*ti[1] + D[i*3+2]*ti[2]);
        Dm[i*4+0] = (float)D[i*3+0];
        Dm[i*4+1] = (float)D[i*3+1];
        Dm[i*4+2] = (float)D[i*3+2];
        Dm[i*4+3] = (float)di;
    }
}

// ---------------- init: T = se3_exp(pose_twist); D = identity-delta ------
__global__ void init_kernel(const float* __restrict__ pose,
                            float* __restrict__ Tcur, float* __restrict__ Tinit,
                            float* __restrict__ Dmat) {
    int b = threadIdx.x;
    if (b >= B_) return;
    double xi[6];
    #pragma unroll
    for (int k = 0; k < 6; ++k) xi[k] = (double)pose[b*6+k];
    double T[16];
    se3_exp_d(xi, T);
    #pragma unroll
    for (int k = 0; k < 16; ++k) {
        float f = (float)T[k];
        Tcur[b*16+k]  = f;
        Tinit[b*16+k] = f;
    }
    write_delta(T, Tinit + b*16, Dmat + b*12);
}

// ---------------- precompute planes -------------------------------------
// P4: .x,.y = v.rgbd (fp16); .z = dx.rgbd (fp8 e4m3); .w = dy.rgbd (fp8).
// XI4: {Xi0, Xi1, Xi2, iD1} fp32 -- iteration-invariant front math.
#define PRE_BPB (HW_/TPB)   // 560
__device__ __forceinline__ unsigned pk16(float a, float b) {
    __half2 h = __floats2half2_rn(a, b);
    unsigned u; __builtin_memcpy(&u, &h, 4); return u;
}
__global__ __launch_bounds__(TPB)
void pack_kernel(const float* __restrict__ I0, const float* __restrict__ invD0,
                 const float* __restrict__ invD1, const float* __restrict__ intr,
                 const float* __restrict__ Tinit,
                 uint4* __restrict__ P4, float4* __restrict__ XI4)
{
    const int b   = blockIdx.x / PRE_BPB;
    const int rem = blockIdx.x % PRE_BPB;
    const int p   = rem*TPB + (int)threadIdx.x;
    const int y   = p / W_;
    const int x   = p - y*W_;
    const int xp  = (x < W_-1) ? 1 : 0;
    const int xm  = (x > 0) ? -1 : 0;
    const int yp  = (y < H_-1) ? W_ : 0;
    const int ym  = (y > 0) ? -W_ : 0;

    const float* s0 = I0    + (size_t)b*C_*HW_ + p;
    const float* sd = invD0 + (size_t)b*HW_   + p;

    const float v0 = s0[0], v1 = s0[HW_], v2 = s0[2*HW_], v3 = sd[0];
    const float dx0 = 0.5f*(s0[xp]       - s0[xm]);
    const float dx1 = 0.5f*(s0[HW_+xp]   - s0[HW_+xm]);
    const float dx2 = 0.5f*(s0[2*HW_+xp] - s0[2*HW_+xm]);
    const float dx3 = 0.5f*(sd[xp]       - sd[xm]);
    const float dy0 = 0.5f*(s0[yp]       - s0[ym]);
    const float dy1 = 0.5f*(s0[HW_+yp]   - s0[HW_+ym]);
    const float dy2 = 0.5f*(s0[2*HW_+yp] - s0[2*HW_+ym]);
    const float dy3 = 0.5f*(sd[yp]       - sd[ym]);

    int zx = 0, zy = 0;
    zx = __builtin_amdgcn_cvt_pk_fp8_f32(dx0, dx1, zx, false);
    zx = __builtin_amdgcn_cvt_pk_fp8_f32(dx2, dx3, zx, true);
    zy = __builtin_amdgcn_cvt_pk_fp8_f32(dy0, dy1, zy, false);
    zy = __builtin_amdgcn_cvt_pk_fp8_f32(dy2, dy3, zy, true);

    P4[(size_t)b*HW_ + p] = make_uint4(pk16(v0,v1), pk16(v2,v3),
                                       (unsigned)zx, (unsigned)zy);

    // Xi = Rinit * backproject(x, y, invD1) + tinit  (reference op order)
    const float fx = intr[b*4+0], fy = intr[b*4+1];
    const float cx = intr[b*4+2], cy = intr[b*4+3];
    const float* Ti = Tinit + b*16;
    const float iD1 = invD1[(size_t)b*HW_ + p];
    const float iD  = fmaxf(iD1, EPS_);
    const float z1  = 1.0f / iD;
    const float x1  = ((float)x - cx)/fx * z1;
    const float y1  = ((float)y - cy)/fy * z1;
    const float Xi0 = Ti[0]*x1 + Ti[1]*y1 + Ti[2]*z1  + Ti[3];
    const float Xi1 = Ti[4]*x1 + Ti[5]*y1 + Ti[6]*z1  + Ti[7];
    const float Xi2 = Ti[8]*x1 + Ti[9]*y1 + Ti[10]*z1 + Ti[11];
    XI4[(size_t)b*HW_ + p] = make_float4(Xi0, Xi1, Xi2, iD1);
}

__device__ __forceinline__ __half2 bc2(unsigned u) {
    __half2 h; __builtin_memcpy(&h, &u, 4); return h;
}
__device__ __forceinline__ float2 h2f(__half2 h) { return __half22float2(h); }

// ---------------- per-pixel GN accumulation (Xi-precomputed front) -------
// R15 structure; the per-body serial head (rcp(iD) -> x1,y1 -> Xi matvec)
// is replaced by a preloaded Xi float4 + one 3x3 matvec Xc = D*Xi + d.
// invD1 load, ucoord/vcoord math gone. Taps/blend/accumulate identical R15.
// NO launch_bounds min-waves (R2/R3/R6 spill history).
__global__ __launch_bounds__(TPB)
void pixel_xi_kernel(const uint4* __restrict__ P4, const float4* __restrict__ XI4,
                     const float* __restrict__ I1,
                     const float* __restrict__ intr,
                     const float* __restrict__ Dmat,
                     float* __restrict__ partials)
{
    // XCD-aware swizzle (bijective, 1792 % 8 == 0): contiguous chunks per XCD.
    const int nwg = B_*BPB;
    const int bid = blockIdx.x;
    const int swz = (bid & 7) * (nwg >> 3) + (bid >> 3);
    const int b   = swz / BPB;
    const int blk = swz % BPB;

    const float fx = intr[b*4+0], fy = intr[b*4+1];
    const float cx = intr[b*4+2], cy = intr[b*4+3];

    const float* Dm = Dmat + b*12;
    const float D00=Dm[0], D01=Dm[1], D02=Dm[2],  d0=Dm[3];
    const float D10=Dm[4], D11=Dm[5], D12=Dm[6],  d1=Dm[7];
    const float D20=Dm[8], D21=Dm[9], D22=Dm[10], d2=Dm[11];

    const uint4*  Pb = P4  + (size_t)b*HW_;
    const float4* Xb = XI4 + (size_t)b*HW_;
    const float*  P1 = I1  + (size_t)b*C_*HW_;

    float acc[27];
    #pragma unroll
    for (int k = 0; k < 27; ++k) acc[k] = 0.0f;

    const int base = blk*CHUNK + (int)threadIdx.x;

    // preload all 5 Xi float4 (coalesced linear loads)
    float4 Xiv[PPT];
    #pragma unroll
    for (int i = 0; i < PPT; ++i) Xiv[i] = Xb[base + i*TPB];

    auto body = [&](int i5) {
        const int p = base + i5*TPB;

        // P1 loads issue first -- independent, overlap the gather wait
        const float p1a = P1[p];
        const float p1b = P1[HW_ + p];
        const float p1c = P1[2*HW_ + p];

        const float4 F = Xiv[i5];
        const float iD1 = F.w;

        // current warp: Xc = D*Xi + d  (== Rc*X1 + tc up to rounding)
        const float Xc0 = D00*F.x + D01*F.y + D02*F.z + d0;
        const float Xc1 = D10*F.x + D11*F.y + D12*F.z + d1;
        const float Xc2 = D20*F.x + D21*F.y + D22*F.z + d2;
        const float z0s = (fabsf(Xc2) > EPS_) ? Xc2 : EPS_;
        const float izc = 1.0f / z0s;
        const float u0  = fx*Xc0*izc + cx;
        const float v0  = fy*Xc1*izc + cy;
        const bool valid = (Xc2 > EPS_) && (iD1 > EPS_);
        const bool inb   = (u0 > 0.0f) && (u0 < (float)(W_-1)) &&
                           (v0 > 0.0f) && (v0 < (float)(H_-1));
        const bool vm = valid && inb;

        // Jacobian scalars from precomputed Xi
        const float zis = (fabsf(F.z) > EPS_) ? F.z : EPS_;
        const float izi = 1.0f / zis;
        const float aJ = fx*izi;
        const float cJ = -fx*F.x*izi*izi;
        const float bJ = fy*izi;
        const float dJ = -fy*F.y*izi*izi;

        // normalized grid (clipped), back to pixel coords -- mirror reference
        const float gx = fminf(fmaxf((u0/(float)(W_-1) - 0.5f)*2.0f, -2.0f), 2.0f);
        const float gy = fminf(fmaxf((v0/(float)(H_-1) - 0.5f)*2.0f, -2.0f), 2.0f);
        const float ix = (gx + 1.0f)*0.5f*(float)(W_-1);
        const float iy = (gy + 1.0f)*0.5f*(float)(H_-1);
        const float x0f = floorf(ix), y0f = floorf(iy);
        const float wx1 = ix - x0f,  wy1 = iy - y0f;
        const float wx0 = 1.0f - wx1, wy0 = 1.0f - wy1;

        // per-tap masks (reference: tap inside [0,W-1]x[0,H-1])
        const bool bx0 = (x0f >= 0.0f)  && (x0f <= (float)(W_-1));
        const bool bx1 = (x0f >= -1.0f) && (x0f <= (float)(W_-2));
        const bool by0 = (y0f >= 0.0f)  && (y0f <= (float)(H_-1));
        const bool by1 = (y0f >= -1.0f) && (y0f <= (float)(H_-2));
        const float m00 = (bx0 && by0) ? wx0*wy0 : 0.0f;
        const float m10 = (bx1 && by0) ? wx1*wy0 : 0.0f;
        const float m01 = (bx0 && by1) ? wx0*wy1 : 0.0f;
        const float m11 = (bx1 && by1) ? wx1*wy1 : 0.0f;

        const int x0i = (int)x0f;
        const int y0i = (int)y0f;
        const int c0 = min(max(x0i,   0), W_-1);
        const int c1 = min(max(x0i+1, 0), W_-1);
        const int o0 = min(max(y0i,   0), H_-1) * W_;
        const int o1 = min(max(y0i+1, 0), H_-1) * W_;

        // single gather batch: 4 x uint4 (one load per tap)
        const uint4 A00 = Pb[o0+c0];
        const uint4 A10 = Pb[o0+c1];
        const uint4 A01 = Pb[o1+c0];
        const uint4 A11 = Pb[o1+c1];

        float sv0=0,sv1=0,sv2=0,sv3=0;
        float gx0=0,gx1=0,gx2=0,gx3=0;
        float gy0=0,gy1=0,gy2=0,gy3=0;
        #define BLEND(A, m) {                                               \
            float2 t;                                                       \
            t = h2f(bc2(A.x)); sv0 += m*t.x; sv1 += m*t.y;                  \
            t = h2f(bc2(A.y)); sv2 += m*t.x; sv3 += m*t.y;                  \
            vfloat2 g0 = __builtin_amdgcn_cvt_pk_f32_fp8((int)A.z, false);  \
            gx0 += m*g0[0]; gx1 += m*g0[1];                                 \
            vfloat2 g1 = __builtin_amdgcn_cvt_pk_f32_fp8((int)A.z, true);   \
            gx2 += m*g1[0]; gx3 += m*g1[1];                                 \
            vfloat2 g2 = __builtin_amdgcn_cvt_pk_f32_fp8((int)A.w, false);  \
            gy0 += m*g2[0]; gy1 += m*g2[1];                                 \
            vfloat2 g3 = __builtin_amdgcn_cvt_pk_f32_fp8((int)A.w, true);   \
            gy2 += m*g3[0]; gy3 += m*g3[1]; }
        BLEND(A00, m00)
        BLEND(A10, m10)
        BLEND(A01, m01)
        BLEND(A11, m11)
        #undef BLEND

        // ---- factorized accumulate: S (3x3 sym) and u over 4 channels ----
        float S00=0,S01=0,S02=0,S11=0,S12=0,S22=0, U0=0,U1=0,U2=0;
        #define PHOTO(SVc, GXc, GYc, P1c) {                            \
            const float r  = vm ? (P1c - SVc) : 1e-6f;                 \
            const float w  = fminf(1.0f, HUBER_ / fmaxf(fabsf(r), EPS_)); \
            const float hx = GXc*aJ, hy = GYc*bJ, hz_ = GXc*cJ + GYc*dJ;  \
            const float whx = w*hx, why = w*hy, wr = w*r;              \
            S00 += whx*hx; S01 += whx*hy; S02 += whx*hz_;              \
            S11 += why*hy; S12 += why*hz_; S22 += w*hz_*hz_;           \
            U0 -= wr*hx; U1 -= wr*hy; U2 -= wr*hz_; }
        PHOTO(sv0, gx0, gy0, p1a)
        PHOTO(sv1, gx1, gy1, p1b)
        PHOTO(sv2, gx2, gy2, p1c)
        #undef PHOTO
        {   // depth channel: J = LAMBDA*(e3 - h_d)*Jt
            const float rz = LAMBDA_*(vm ? (izc - sv3) : 1e-6f);
            const float w  = fminf(1.0f, HUBER_ / fmaxf(fabsf(rz), EPS_));
            const float hx = gx3*aJ, hy = gy3*bJ, hz_ = gx3*cJ + gy3*dJ;
            const float qx = -hx, qy = -hy, qz = 1.0f - hz_;
            const float wl2 = w*(LAMBDA_*LAMBDA_);
            const float wqx = wl2*qx, wqy = wl2*qy;
            S00 += wqx*qx; S01 += wqx*qy; S02 += wqx*qz;
            S11 += wqy*qy; S12 += wqy*qz; S22 += wl2*qz*qz;
            const float wrl = w*rz*LAMBDA_;
            U0 += wrl*qx; U1 += wrl*qy; U2 += wrl*qz;
        }
        // expand via Jt = [I | -K], K = skew(Xi): M=[[S,-SK],[.,K'SK]]
        const float x = F.x, y = F.y, z = F.z;
        const float P00 =  S01*z - S02*y, P01 = -S00*z + S02*x, P02 =  S00*y - S01*x;
        const float P10 =  S11*z - S12*y, P11 = -S01*z + S12*x, P12 =  S01*y - S11*x;
        const float P20 =  S12*z - S22*y, P21 = -S02*z + S22*x, P22 =  S02*y - S12*x;
        const float Q00 =  z*P10 - y*P20, Q01 =  z*P11 - y*P21, Q02 =  z*P12 - y*P22;
        const float Q11 = -z*P01 + x*P21, Q12 = -z*P02 + x*P22;
        const float Q22 =  y*P02 - x*P12;
        acc[0]  += S00; acc[1]  += S01; acc[2]  += S02;
        acc[3]  += S11; acc[4]  += S12; acc[5]  += S22;
        acc[6]  -= P00; acc[7]  -= P01; acc[8]  -= P02;
        acc[9]  -= P10; acc[10] -= P11; acc[11] -= P12;
        acc[12] -= P20; acc[13] -= P21; acc[14] -= P22;
        acc[15] += Q00; acc[16] += Q01; acc[17] += Q02;
        acc[18] += Q11; acc[19] += Q12; acc[20] += Q22;
        acc[21] += U0; acc[22] += U1; acc[23] += U2;
        acc[24] += y*U2 - z*U1;
        acc[25] += z*U0 - x*U2;
        acc[26] += x*U1 - y*U0;
    };

    #pragma unroll
    for (int i5 = 0; i5 < PPT; ++i5)
        body(i5);

    // wave (64-lane) reduction in float
    #pragma unroll
    for (int off = 32; off >= 1; off >>= 1) {
        #pragma unroll
        for (int k = 0; k < 27; ++k)
            acc[k] += __shfl_down(acc[k], off);
    }
    __shared__ float red[TPB/64][27];
    const int lane = threadIdx.x & 63;
    const int wid  = threadIdx.x >> 6;
    if (lane == 0) {
        #pragma unroll
        for (int k = 0; k < 27; ++k) red[wid][k] = acc[k];
    }
    __syncthreads();
    if (threadIdx.x < 27) {
        float s = red[0][threadIdx.x] + red[1][threadIdx.x]
                + red[2][threadIdx.x] + red[3][threadIdx.x];
        partials[((size_t)b*BPB + blk)*27 + threadIdx.x] = s;
    }
}

// ---------------- reduce partials, solve 6x6, update T + delta ----------
// partials layout: 0-5 S upper; 6-14 topright 3x3 row-major; 15-20 BR upper;
// 21-26 rhs.
__global__ void solve_kernel(const float* __restrict__ partials,
                             const float* __restrict__ Tinit,
                             float* __restrict__ Tcur, float* __restrict__ Dmat,
                             float* __restrict__ out)
{
    const int b = blockIdx.x;
    __shared__ double S[27];
    const int t = threadIdx.x;
    if (t < 27) {
        double s = 0.0;
        const float* pp = partials + (size_t)b*BPB*27 + t;
        for (int blk = 0; blk < BPB; ++blk) s += (double)pp[blk*27];
        S[t] = s;
    }
    __syncthreads();
    if (t == 0) {
        double Hm[6][6], rhs[6];
        Hm[0][0]=S[0];  Hm[0][1]=S[1];  Hm[0][2]=S[2];
        Hm[1][1]=S[3];  Hm[1][2]=S[4];  Hm[2][2]=S[5];
        for (int i = 0; i < 3; ++i)
            for (int j = 0; j < 3; ++j)
                Hm[i][3+j] = S[6 + i*3 + j];
        Hm[3][3]=S[15]; Hm[3][4]=S[16]; Hm[3][5]=S[17];
        Hm[4][4]=S[18]; Hm[4][5]=S[19]; Hm[5][5]=S[20];
        for (int i = 0; i < 6; ++i)
            for (int j = 0; j < i; ++j) Hm[i][j] = Hm[j][i];
        for (int i = 0; i < 6; ++i) rhs[i] = S[21+i];

        double tr = 0.0;
        for (int i = 0; i < 6; ++i) tr += Hm[i][i];
        const double damp = tr*1e-6;
        for (int i = 0; i < 6; ++i) Hm[i][i] += damp;

        double M[6][7];
        for (int i = 0; i < 6; ++i) {
            for (int j = 0; j < 6; ++j) M[i][j] = Hm[i][j];
            M[i][6] = rhs[i];
        }
        for (int col = 0; col < 6; ++col) {
            int piv = col; double mx = fabs(M[col][col]);
            for (int r2 = col+1; r2 < 6; ++r2) {
                double a2 = fabs(M[r2][col]);
                if (a2 > mx) { mx = a2; piv = r2; }
            }
            if (piv != col)
                for (int j = col; j < 7; ++j) {
                    double tmp = M[col][j]; M[col][j] = M[piv][j]; M[piv][j] = tmp;
                }
            const double inv = 1.0 / M[col][col];
            for (int r2 = col+1; r2 < 6; ++r2) {
                const double f = M[r2][col]*inv;
                for (int j = col; j < 7; ++j) M[r2][j] -= f*M[col][j];
            }
        }
        double xi[6];
        for (int i = 5; i >= 0; --i) {
            double s2 = M[i][6];
            for (int j = i+1; j < 6; ++j) s2 -= M[i][j]*xi[j];
            xi[i] = s2 / M[i][i];
        }
        double nxi[6];
        for (int i = 0; i < 6; ++i) nxi[i] = -xi[i];
        double E[16];
        se3_exp_d(nxi, E);

        double Tc[16], Tn[16];
        for (int k = 0; k < 16; ++k) Tc[k] = (double)Tcur[b*16+k];
        for (int i = 0; i < 4; ++i)
            for (int j = 0; j < 4; ++j) {
                double s2 = 0.0;
                for (int k = 0; k < 4; ++k) s2 += Tc[i*4+k]*E[k*4+j];
                Tn[i*4+j] = s2;
                const float f = (float)s2;
                Tcur[b*16 + i*4 + j] = f;
                out[b*16 + i*4 + j]  = f;
            }
        write_delta(Tn, Tinit + b*16, Dmat + b*12);
    }
}

extern "C" void kernel_launch(void* const* d_in, const int* in_sizes, int n_in,
                              void* d_out, int out_size, void* d_ws, size_t ws_size,
                              hipStream_t stream) {
    const float* pose  = (const float*)d_in[0];
    const float* I0    = (const float*)d_in[1];
    const float* I1    = (const float*)d_in[2];
    const float* invD0 = (const float*)d_in[3];
    const float* invD1 = (const float*)d_in[4];
    const float* intr  = (const float*)d_in[5];
    float* out = (float*)d_out;

    float*  Tcur     = (float*)d_ws;
    float*  Tinit    = Tcur + 256;
    float*  partials = (float*)((char*)d_ws + PARTIALS_OFF);
    float*  Dmat     = (float*)((char*)d_ws + DMAT_OFF);
    uint4*  P4       = (uint4*)((char*)d_ws + PLANE_OFF);
    float4* XI4      = (float4*)((char*)d_ws + XI_OFF);

    hipLaunchKernelGGL(init_kernel, dim3(1), dim3(64), 0, stream,
                       pose, Tcur, Tinit, Dmat);
    hipLaunchKernelGGL(pack_kernel, dim3(B_*PRE_BPB), dim3(TPB), 0, stream,
                       I0, invD0, invD1, intr, Tinit, P4, XI4);
    for (int it = 0; it < NITERS_; ++it) {
        hipLaunchKernelGGL(pixel_xi_kernel, dim3(B_*BPB), dim3(TPB), 0, stream,
                           P4, XI4, I1, intr, Dmat, partials);
        hipLaunchKernelGGL(solve_kernel, dim3(B_), dim3(64), 0, stream,
                           partials, Tinit, Tcur, Dmat, out);
    }
}

// Round 17
// 265.579 us; speedup vs baseline: 1.0904x; 1.0106x over previous
//
#include <hip/hip_runtime.h>
#include <hip/hip_fp16.h>
#include <math.h>

#define B_ 16
#define C_ 3
#define H_ 320
#define W_ 448
#define HW_ (H_*W_)
#define NITERS_ 5
#define LAMBDA_ 0.01f
#define HUBER_ 0.1f
#define EPS_ 1e-6f

#define BPB 112       // blocks per batch (1792 total) -- proven shape
#define CHUNK 1280    // pixels per block == 5*TPB; 112*1280 == H*W
#define TPB 256
#define PPT 5

// workspace layout
#define PARTIALS_OFF 2048            // 16*112*27*4 ~ 189KB
#define DMAT_OFF     200704          // 16 batches x 12 floats
#define PLANE_OFF    262144
#define PLANE_U4     ((size_t)B_*HW_)              // uint4 elements (16B/px)
#define XI_OFF       (PLANE_OFF + PLANE_U4*16)     // float4 Xi plane (16B/px)

typedef __attribute__((__vector_size__(2 * sizeof(float)))) float vfloat2;

// ---------------- SE(3) exp in double ----------------
__device__ __host__ inline void se3_exp_d(const double xi[6], double T[16]) {
    double vx = xi[0], vy = xi[1], vz = xi[2];
    double wx = xi[3], wy = xi[4], wz = xi[5];
    double th2  = wx*wx + wy*wy + wz*wz;
    double th2c = th2 > 1e-16 ? th2 : 1e-16;
    double th   = sqrt(th2c);
    bool   sm   = th2 < 1e-10;
    double A  = sm ? (1.0 - th2*(1.0/6.0))   : (sin(th)/th);
    double Bc = sm ? (0.5 - th2*(1.0/24.0))  : ((1.0 - cos(th))/th2c);
    double Cc = sm ? (1.0/6.0 - th2*(1.0/120.0)) : ((1.0 - A)/th2c);
    double K[9]  = {0.0,-wz,wy,  wz,0.0,-wx,  -wy,wx,0.0};
    double K2[9];
    #pragma unroll
    for (int i = 0; i < 3; ++i)
        #pragma unroll
        for (int j = 0; j < 3; ++j) {
            double s = 0.0;
            #pragma unroll
            for (int k = 0; k < 3; ++k) s += K[i*3+k]*K[k*3+j];
            K2[i*3+j] = s;
        }
    double R[9], V[9];
    #pragma unroll
    for (int i = 0; i < 9; ++i) {
        double I = (i == 0 || i == 4 || i == 8) ? 1.0 : 0.0;
        R[i] = I + A*K[i]  + Bc*K2[i];
        V[i] = I + Bc*K[i] + Cc*K2[i];
    }
    double tx = V[0]*vx + V[1]*vy + V[2]*vz;
    double ty = V[3]*vx + V[4]*vy + V[5]*vz;
    double tz = V[6]*vx + V[7]*vy + V[8]*vz;
    T[0]=R[0]; T[1]=R[1]; T[2] =R[2]; T[3] =tx;
    T[4]=R[3]; T[5]=R[4]; T[6] =R[5]; T[7] =ty;
    T[8]=R[6]; T[9]=R[7]; T[10]=R[8]; T[11]=tz;
    T[12]=0.0; T[13]=0.0; T[14]=0.0;  T[15]=1.0;
}

// D = Rcur * Rinit^T ; d = tcur - D * tinit
__device__ inline void write_delta(const double Tc[16], const float* Ti,
                                   float* Dm) {
    double Ri[9], ti[3];
    Ri[0]=Ti[0]; Ri[1]=Ti[1]; Ri[2]=Ti[2];  ti[0]=Ti[3];
    Ri[3]=Ti[4]; Ri[4]=Ti[5]; Ri[5]=Ti[6];  ti[1]=Ti[7];
    Ri[6]=Ti[8]; Ri[7]=Ti[9]; Ri[8]=Ti[10]; ti[2]=Ti[11];
    double D[9];
    #pragma unroll
    for (int i = 0; i < 3; ++i)
        #pragma unroll
        for (int j = 0; j < 3; ++j)
            D[i*3+j] = Tc[i*4+0]*Ri[j*3+0] + Tc[i*4+1]*Ri[j*3+1] + Tc[i*4+2]*Ri[j*3+2];
    #pragma unroll
    for (int i = 0; i < 3; ++i) {
        const double di = Tc[i*4+3] - (D[i*3+0]*ti[0] + D[i*3+1]*ti[1] + D[i*3+2]*ti[2]);
        Dm[i*4+0] = (float)D[i*3+0];
        Dm[i*4+1] = (float)D[i*3+1];
        Dm[i*4+2] = (float)D[i*3+2];
        Dm[i*4+3] = (float)di;
    }
}

// ---------------- init ----------------
__global__ void init_kernel(const float* __restrict__ pose,
                            float* __restrict__ Tcur, float* __restrict__ Tinit,
                            float* __restrict__ Dmat) {
    int b = threadIdx.x;
    if (b >= B_) return;
    double xi[6];
    #pragma unroll
    for (int k = 0; k < 6; ++k) xi[k] = (double)pose[b*6+k];
    double T[16];
    se3_exp_d(xi, T);
    #pragma unroll
    for (int k = 0; k < 16; ++k) {
        float f = (float)T[k];
        Tcur[b*16+k]  = f;
        Tinit[b*16+k] = f;
    }
    write_delta(T, Tinit + b*16, Dmat + b*12);
}

// ---------------- precompute planes -------------------------------------
#define PRE_BPB (HW_/TPB)   // 560
__device__ __forceinline__ unsigned pk16(float a, float b) {
    __half2 h = __floats2half2_rn(a, b);
    unsigned u; __builtin_memcpy(&u, &h, 4); return u;
}
__global__ __launch_bounds__(TPB)
void pack_kernel(const float* __restrict__ I0, const float* __restrict__ invD0,
                 const float* __restrict__ invD1, const float* __restrict__ intr,
                 const float* __restrict__ Tinit,
                 uint4* __restrict__ P4, float4* __restrict__ XI4)
{
    const int b   = blockIdx.x / PRE_BPB;
    const int rem = blockIdx.x % PRE_BPB;
    const int p   = rem*TPB + (int)threadIdx.x;
    const int y   = p / W_;
    const int x   = p - y*W_;
    const int xp  = (x < W_-1) ? 1 : 0;
    const int xm  = (x > 0) ? -1 : 0;
    const int yp  = (y < H_-1) ? W_ : 0;
    const int ym  = (y > 0) ? -W_ : 0;

    const float* s0 = I0    + (size_t)b*C_*HW_ + p;
    const float* sd = invD0 + (size_t)b*HW_   + p;

    const float v0 = s0[0], v1 = s0[HW_], v2 = s0[2*HW_], v3 = sd[0];
    const float dx0 = 0.5f*(s0[xp]       - s0[xm]);
    const float dx1 = 0.5f*(s0[HW_+xp]   - s0[HW_+xm]);
    const float dx2 = 0.5f*(s0[2*HW_+xp] - s0[2*HW_+xm]);
    const float dx3 = 0.5f*(sd[xp]       - sd[xm]);
    const float dy0 = 0.5f*(s0[yp]       - s0[ym]);
    const float dy1 = 0.5f*(s0[HW_+yp]   - s0[HW_+ym]);
    const float dy2 = 0.5f*(s0[2*HW_+yp] - s0[2*HW_+ym]);
    const float dy3 = 0.5f*(sd[yp]       - sd[ym]);

    int zx = 0, zy = 0;
    zx = __builtin_amdgcn_cvt_pk_fp8_f32(dx0, dx1, zx, false);
    zx = __builtin_amdgcn_cvt_pk_fp8_f32(dx2, dx3, zx, true);
    zy = __builtin_amdgcn_cvt_pk_fp8_f32(dy0, dy1, zy, false);
    zy = __builtin_amdgcn_cvt_pk_fp8_f32(dy2, dy3, zy, true);

    P4[(size_t)b*HW_ + p] = make_uint4(pk16(v0,v1), pk16(v2,v3),
                                       (unsigned)zx, (unsigned)zy);

    // Xi = Rinit * backproject(x, y, invD1) + tinit  (reference op order)
    const float fx = intr[b*4+0], fy = intr[b*4+1];
    const float cx = intr[b*4+2], cy = intr[b*4+3];
    const float* Ti = Tinit + b*16;
    const float iD1 = invD1[(size_t)b*HW_ + p];
    const float iD  = fmaxf(iD1, EPS_);
    const float z1  = 1.0f / iD;
    const float x1  = ((float)x - cx)/fx * z1;
    const float y1  = ((float)y - cy)/fy * z1;
    const float Xi0 = Ti[0]*x1 + Ti[1]*y1 + Ti[2]*z1  + Ti[3];
    const float Xi1 = Ti[4]*x1 + Ti[5]*y1 + Ti[6]*z1  + Ti[7];
    const float Xi2 = Ti[8]*x1 + Ti[9]*y1 + Ti[10]*z1 + Ti[11];
    XI4[(size_t)b*HW_ + p] = make_float4(Xi0, Xi1, Xi2, iD1);
}

__device__ __forceinline__ __half2 bc2(unsigned u) {
    __half2 h; __builtin_memcpy(&h, &u, 4); return h;
}
__device__ __forceinline__ float2 h2f(__half2 h) { return __half22float2(h); }

// per-body front state (small: 4 masks + 4 scalars + izc + vm + 2 offsets)
struct Front {
    float m00, m10, m01, m11;
    float aJ, bJ, cJ, dJ;
    float izc;
    float x, y, z;      // Xi
    int   q00, q10, q01, q11;
    bool  vm;
};

// ---------------- per-pixel GN accumulation (paired load batches) --------
// Bodies processed in PAIRS: both fronts computed, then 8 tap loads + 6 P1
// loads issued together (2x independent-loads-in-flight per wait vs R16).
// Xi loaded in-body (linear coalesced) to pay the VGPR bill for the second
// tap batch -- R8's failure was 132 VGPR from buffered arrays; this is
// budgeted to stay in the 65-128 tier. NO launch_bounds min-waves.
__global__ __launch_bounds__(TPB)
void pixel_pair_kernel(const uint4* __restrict__ P4, const float4* __restrict__ XI4,
                       const float* __restrict__ I1,
                       const float* __restrict__ intr,
                       const float* __restrict__ Dmat,
                       float* __restrict__ partials)
{
    const int nwg = B_*BPB;
    const int bid = blockIdx.x;
    const int swz = (bid & 7) * (nwg >> 3) + (bid >> 3);
    const int b   = swz / BPB;
    const int blk = swz % BPB;

    const float fx = intr[b*4+0], fy = intr[b*4+1];
    const float cx = intr[b*4+2], cy = intr[b*4+3];

    const float* Dm = Dmat + b*12;
    const float D00=Dm[0], D01=Dm[1], D02=Dm[2],  d0=Dm[3];
    const float D10=Dm[4], D11=Dm[5], D12=Dm[6],  d1=Dm[7];
    const float D20=Dm[8], D21=Dm[9], D22=Dm[10], d2=Dm[11];

    const uint4*  Pb = P4  + (size_t)b*HW_;
    const float4* Xb = XI4 + (size_t)b*HW_;
    const float*  P1 = I1  + (size_t)b*C_*HW_;

    float acc[27];
    #pragma unroll
    for (int k = 0; k < 27; ++k) acc[k] = 0.0f;

    const int base = blk*CHUNK + (int)threadIdx.x;

    // front math for one body (from its Xi float4)
    auto front = [&](const float4 F, Front& S) {
        const float iD1 = F.w;
        const float Xc0 = D00*F.x + D01*F.y + D02*F.z + d0;
        const float Xc1 = D10*F.x + D11*F.y + D12*F.z + d1;
        const float Xc2 = D20*F.x + D21*F.y + D22*F.z + d2;
        const float z0s = (fabsf(Xc2) > EPS_) ? Xc2 : EPS_;
        const float izc = 1.0f / z0s;
        const float u0  = fx*Xc0*izc + cx;
        const float v0  = fy*Xc1*izc + cy;
        const bool valid = (Xc2 > EPS_) && (iD1 > EPS_);
        const bool inb   = (u0 > 0.0f) && (u0 < (float)(W_-1)) &&
                           (v0 > 0.0f) && (v0 < (float)(H_-1));
        S.vm  = valid && inb;
        S.izc = izc;

        const float zis = (fabsf(F.z) > EPS_) ? F.z : EPS_;
        const float izi = 1.0f / zis;
        S.aJ = fx*izi;
        S.cJ = -fx*F.x*izi*izi;
        S.bJ = fy*izi;
        S.dJ = -fy*F.y*izi*izi;
        S.x = F.x; S.y = F.y; S.z = F.z;

        const float gx = fminf(fmaxf((u0/(float)(W_-1) - 0.5f)*2.0f, -2.0f), 2.0f);
        const float gy = fminf(fmaxf((v0/(float)(H_-1) - 0.5f)*2.0f, -2.0f), 2.0f);
        const float ix = (gx + 1.0f)*0.5f*(float)(W_-1);
        const float iy = (gy + 1.0f)*0.5f*(float)(H_-1);
        const float x0f = floorf(ix), y0f = floorf(iy);
        const float wx1 = ix - x0f,  wy1 = iy - y0f;
        const float wx0 = 1.0f - wx1, wy0 = 1.0f - wy1;

        const bool bx0 = (x0f >= 0.0f)  && (x0f <= (float)(W_-1));
        const bool bx1 = (x0f >= -1.0f) && (x0f <= (float)(W_-2));
        const bool by0 = (y0f >= 0.0f)  && (y0f <= (float)(H_-1));
        const bool by1 = (y0f >= -1.0f) && (y0f <= (float)(H_-2));
        S.m00 = (bx0 && by0) ? wx0*wy0 : 0.0f;
        S.m10 = (bx1 && by0) ? wx1*wy0 : 0.0f;
        S.m01 = (bx0 && by1) ? wx0*wy1 : 0.0f;
        S.m11 = (bx1 && by1) ? wx1*wy1 : 0.0f;

        const int x0i = (int)x0f;
        const int y0i = (int)y0f;
        const int c0 = min(max(x0i,   0), W_-1);
        const int c1 = min(max(x0i+1, 0), W_-1);
        const int o0 = min(max(y0i,   0), H_-1) * W_;
        const int o1 = min(max(y0i+1, 0), H_-1) * W_;
        S.q00 = o0+c0; S.q10 = o0+c1; S.q01 = o1+c0; S.q11 = o1+c1;
    };

    // accumulate one body from its 4 taps
    auto accum = [&](const Front& S, const uint4 A00, const uint4 A10,
                     const uint4 A01, const uint4 A11,
                     const float p1a, const float p1b, const float p1c) {
        float sv0=0,sv1=0,sv2=0,sv3=0;
        float gx0=0,gx1=0,gx2=0,gx3=0;
        float gy0=0,gy1=0,gy2=0,gy3=0;
        #define BLEND(A, m) {                                               \
            float2 t;                                                       \
            t = h2f(bc2(A.x)); sv0 += m*t.x; sv1 += m*t.y;                  \
            t = h2f(bc2(A.y)); sv2 += m*t.x; sv3 += m*t.y;                  \
            vfloat2 g0 = __builtin_amdgcn_cvt_pk_f32_fp8((int)A.z, false);  \
            gx0 += m*g0[0]; gx1 += m*g0[1];                                 \
            vfloat2 g1 = __builtin_amdgcn_cvt_pk_f32_fp8((int)A.z, true);   \
            gx2 += m*g1[0]; gx3 += m*g1[1];                                 \
            vfloat2 g2 = __builtin_amdgcn_cvt_pk_f32_fp8((int)A.w, false);  \
            gy0 += m*g2[0]; gy1 += m*g2[1];                                 \
            vfloat2 g3 = __builtin_amdgcn_cvt_pk_f32_fp8((int)A.w, true);   \
            gy2 += m*g3[0]; gy3 += m*g3[1]; }
        BLEND(A00, S.m00)
        BLEND(A10, S.m10)
        BLEND(A01, S.m01)
        BLEND(A11, S.m11)
        #undef BLEND

        float S00=0,S01=0,S02=0,S11=0,S12=0,S22=0, U0=0,U1=0,U2=0;
        #define PHOTO(SVc, GXc, GYc, P1c) {                            \
            const float r  = S.vm ? (P1c - SVc) : 1e-6f;               \
            const float w  = fminf(1.0f, HUBER_ / fmaxf(fabsf(r), EPS_)); \
            const float hx = GXc*S.aJ, hy = GYc*S.bJ,                  \
                        hz_ = GXc*S.cJ + GYc*S.dJ;                     \
            const float whx = w*hx, why = w*hy, wr = w*r;              \
            S00 += whx*hx; S01 += whx*hy; S02 += whx*hz_;              \
            S11 += why*hy; S12 += why*hz_; S22 += w*hz_*hz_;           \
            U0 -= wr*hx; U1 -= wr*hy; U2 -= wr*hz_; }
        PHOTO(sv0, gx0, gy0, p1a)
        PHOTO(sv1, gx1, gy1, p1b)
        PHOTO(sv2, gx2, gy2, p1c)
        #undef PHOTO
        {
            const float rz = LAMBDA_*(S.vm ? (S.izc - sv3) : 1e-6f);
            const float w  = fminf(1.0f, HUBER_ / fmaxf(fabsf(rz), EPS_));
            const float hx = gx3*S.aJ, hy = gy3*S.bJ, hz_ = gx3*S.cJ + gy3*S.dJ;
            const float qx = -hx, qy = -hy, qz = 1.0f - hz_;
            const float wl2 = w*(LAMBDA_*LAMBDA_);
            const float wqx = wl2*qx, wqy = wl2*qy;
            S00 += wqx*qx; S01 += wqx*qy; S02 += wqx*qz;
            S11 += wqy*qy; S12 += wqy*qz; S22 += wl2*qz*qz;
            const float wrl = w*rz*LAMBDA_;
            U0 += wrl*qx; U1 += wrl*qy; U2 += wrl*qz;
        }
        const float x = S.x, y = S.y, z = S.z;
        const float P00 =  S01*z - S02*y, P01 = -S00*z + S02*x, P02 =  S00*y - S01*x;
        const float P10 =  S11*z - S12*y, P11 = -S01*z + S12*x, P12 =  S01*y - S11*x;
        const float P20 =  S12*z - S22*y, P21 = -S02*z + S22*x, P22 =  S02*y - S12*x;
        const float Q00 =  z*P10 - y*P20, Q01 =  z*P11 - y*P21, Q02 =  z*P12 - y*P22;
        const float Q11 = -z*P01 + x*P21, Q12 = -z*P02 + x*P22;
        const float Q22 =  y*P02 - x*P12;
        acc[0]  += S00; acc[1]  += S01; acc[2]  += S02;
        acc[3]  += S11; acc[4]  += S12; acc[5]  += S22;
        acc[6]  -= P00; acc[7]  -= P01; acc[8]  -= P02;
        acc[9]  -= P10; acc[10] -= P11; acc[11] -= P12;
        acc[12] -= P20; acc[13] -= P21; acc[14] -= P22;
        acc[15] += Q00; acc[16] += Q01; acc[17] += Q02;
        acc[18] += Q11; acc[19] += Q12; acc[20] += Q22;
        acc[21] += U0; acc[22] += U1; acc[23] += U2;
        acc[24] += y*U2 - z*U1;
        acc[25] += z*U0 - x*U2;
        acc[26] += x*U1 - y*U0;
    };

    // ---- pairs (0,1), (2,3) ----
    #pragma unroll
    for (int pr = 0; pr < 2; ++pr) {
        const int pA = base + (2*pr)*TPB;
        const int pB = base + (2*pr+1)*TPB;
        // linear loads first (Xi x2, P1 x6) -- all independent
        const float4 FA = Xb[pA];
        const float4 FB = Xb[pB];
        const float a1 = P1[pA], a2 = P1[HW_+pA], a3 = P1[2*HW_+pA];
        const float b1 = P1[pB], b2 = P1[HW_+pB], b3 = P1[2*HW_+pB];
        Front SA, SB;
        front(FA, SA);
        front(FB, SB);
        // 8 tap loads issued together -- 2x window vs single-body
        const uint4 A00 = Pb[SA.q00], A10 = Pb[SA.q10];
        const uint4 A01 = Pb[SA.q01], A11 = Pb[SA.q11];
        const uint4 B00 = Pb[SB.q00], B10 = Pb[SB.q10];
        const uint4 B01 = Pb[SB.q01], B11 = Pb[SB.q11];
        accum(SA, A00, A10, A01, A11, a1, a2, a3);
        accum(SB, B00, B10, B01, B11, b1, b2, b3);
    }
    // ---- tail body (4) ----
    {
        const int p = base + 4*TPB;
        const float4 F = Xb[p];
        const float a1 = P1[p], a2 = P1[HW_+p], a3 = P1[2*HW_+p];
        Front S;
        front(F, S);
        const uint4 A00 = Pb[S.q00], A10 = Pb[S.q10];
        const uint4 A01 = Pb[S.q01], A11 = Pb[S.q11];
        accum(S, A00, A10, A01, A11, a1, a2, a3);
    }

    // wave (64-lane) reduction in float
    #pragma unroll
    for (int off = 32; off >= 1; off >>= 1) {
        #pragma unroll
        for (int k = 0; k < 27; ++k)
            acc[k] += __shfl_down(acc[k], off);
    }
    __shared__ float red[TPB/64][27];
    const int lane = threadIdx.x & 63;
    const int wid  = threadIdx.x >> 6;
    if (lane == 0) {
        #pragma unroll
        for (int k = 0; k < 27; ++k) red[wid][k] = acc[k];
    }
    __syncthreads();
    if (threadIdx.x < 27) {
        float s = red[0][threadIdx.x] + red[1][threadIdx.x]
                + red[2][threadIdx.x] + red[3][threadIdx.x];
        partials[((size_t)b*BPB + blk)*27 + threadIdx.x] = s;
    }
}

// ---------------- reduce partials, solve 6x6, update T + delta ----------
__global__ void solve_kernel(const float* __restrict__ partials,
                             const float* __restrict__ Tinit,
                             float* __restrict__ Tcur, float* __restrict__ Dmat,
                             float* __restrict__ out)
{
    const int b = blockIdx.x;
    __shared__ double S[27];
    const int t = threadIdx.x;
    if (t < 27) {
        double s = 0.0;
        const float* pp = partials + (size_t)b*BPB*27 + t;
        for (int blk = 0; blk < BPB; ++blk) s += (double)pp[blk*27];
        S[t] = s;
    }
    __syncthreads();
    if (t == 0) {
        double Hm[6][6], rhs[6];
        Hm[0][0]=S[0];  Hm[0][1]=S[1];  Hm[0][2]=S[2];
        Hm[1][1]=S[3];  Hm[1][2]=S[4];  Hm[2][2]=S[5];
        for (int i = 0; i < 3; ++i)
            for (int j = 0; j < 3; ++j)
                Hm[i][3+j] = S[6 + i*3 + j];
        Hm[3][3]=S[15]; Hm[3][4]=S[16]; Hm[3][5]=S[17];
        Hm[4][4]=S[18]; Hm[4][5]=S[19]; Hm[5][5]=S[20];
        for (int i = 0; i < 6; ++i)
            for (int j = 0; j < i; ++j) Hm[i][j] = Hm[j][i];
        for (int i = 0; i < 6; ++i) rhs[i] = S[21+i];

        double tr = 0.0;
        for (int i = 0; i < 6; ++i) tr += Hm[i][i];
        const double damp = tr*1e-6;
        for (int i = 0; i < 6; ++i) Hm[i][i] += damp;

        double M[6][7];
        for (int i = 0; i < 6; ++i) {
            for (int j = 0; j < 6; ++j) M[i][j] = Hm[i][j];
            M[i][6] = rhs[i];
        }
        for (int col = 0; col < 6; ++col) {
            int piv = col; double mx = fabs(M[col][col]);
            for (int r2 = col+1; r2 < 6; ++r2) {
                double a2 = fabs(M[r2][col]);
                if (a2 > mx) { mx = a2; piv = r2; }
            }
            if (piv != col)
                for (int j = col; j < 7; ++j) {
                    double tmp = M[col][j]; M[col][j] = M[piv][j]; M[piv][j] = tmp;
                }
            const double inv = 1.0 / M[col][col];
            for (int r2 = col+1; r2 < 6; ++r2) {
                const double f = M[r2][col]*inv;
                for (int j = col; j < 7; ++j) M[r2][j] -= f*M[col][j];
            }
        }
        double xi[6];
        for (int i = 5; i >= 0; --i) {
            double s2 = M[i][6];
            for (int j = i+1; j < 6; ++j) s2 -= M[i][j]*xi[j];
            xi[i] = s2 / M[i][i];
        }
        double nxi[6];
        for (int i = 0; i < 6; ++i) nxi[i] = -xi[i];
        double E[16];
        se3_exp_d(nxi, E);

        double Tc[16], Tn[16];
        for (int k = 0; k < 16; ++k) Tc[k] = (double)Tcur[b*16+k];
        for (int i = 0; i < 4; ++i)
            for (int j = 0; j < 4; ++j) {
                double s2 = 0.0;
                for (int k = 0; k < 4; ++k) s2 += Tc[i*4+k]*E[k*4+j];
                Tn[i*4+j] = s2;
                const float f = (float)s2;
                Tcur[b*16 + i*4 + j] = f;
                out[b*16 + i*4 + j]  = f;
            }
        write_delta(Tn, Tinit + b*16, Dmat + b*12);
    }
}

extern "C" void kernel_launch(void* const* d_in, const int* in_sizes, int n_in,
                              void* d_out, int out_size, void* d_ws, size_t ws_size,
                              hipStream_t stream) {
    const float* pose  = (const float*)d_in[0];
    const float* I0    = (const float*)d_in[1];
    const float* I1    = (const float*)d_in[2];
    const float* invD0 = (const float*)d_in[3];
    const float* invD1 = (const float*)d_in[4];
    const float* intr  = (const float*)d_in[5];
    float* out = (float*)d_out;

    float*  Tcur     = (float*)d_ws;
    float*  Tinit    = Tcur + 256;
    float*  partials = (float*)((char*)d_ws + PARTIALS_OFF);
    float*  Dmat     = (float*)((char*)d_ws + DMAT_OFF);
    uint4*  P4       = (uint4*)((char*)d_ws + PLANE_OFF);
    float4* XI4      = (float4*)((char*)d_ws + XI_OFF);

    hipLaunchKernelGGL(init_kernel, dim3(1), dim3(64), 0, stream,
                       pose, Tcur, Tinit, Dmat);
    hipLaunchKernelGGL(pack_kernel, dim3(B_*PRE_BPB), dim3(TPB), 0, stream,
                       I0, invD0, invD1, intr, Tinit, P4, XI4);
    for (int it = 0; it < NITERS_; ++it) {
        hipLaunchKernelGGL(pixel_pair_kernel, dim3(B_*BPB), dim3(TPB), 0, stream,
                           P4, XI4, I1, intr, Dmat, partials);
        hipLaunchKernelGGL(solve_kernel, dim3(B_), dim3(64), 0, stream,
                           partials, Tinit, Tcur, Dmat, out);
    }
}